// Round 1
// baseline (2909.192 us; speedup 1.0000x reference)
//
#include <hip/hip_runtime.h>
#include <float.h>
#include <math.h>

#define BB 64
#define NN 4096
#define EE 32768
#define FIN 12
#define HD 64
#define KK1 3277
#define KK2 2622

// ---------------- conv1: scatter-add raw 12-dim features over edges ----------
__global__ __launch_bounds__(256) void k_conv1(const float* __restrict__ x,
    const int* __restrict__ ei, float* __restrict__ agg12, int g0) {
  int s = blockIdx.x >> 7;                 // 128 blocks per graph
  int e = ((blockIdx.x & 127) << 8) + threadIdx.x;
  int g = g0 + s;
  const int* eg = ei + (size_t)g * 2 * EE;
  int src = eg[e], dst = eg[EE + e];
  const float4* xs = (const float4*)(x + ((size_t)g * NN + src) * FIN);
  float* ad = agg12 + ((size_t)s * NN + dst) * FIN;
  float4 a = xs[0], b = xs[1], c = xs[2];
  atomicAdd(ad + 0, a.x);  atomicAdd(ad + 1, a.y);
  atomicAdd(ad + 2, a.z);  atomicAdd(ad + 3, a.w);
  atomicAdd(ad + 4, b.x);  atomicAdd(ad + 5, b.y);
  atomicAdd(ad + 6, b.z);  atomicAdd(ad + 7, b.w);
  atomicAdd(ad + 8, c.x);  atomicAdd(ad + 9, c.y);
  atomicAdd(ad + 10, c.z); atomicAdd(ad + 11, c.w);
}

// ---------------- h1 = relu(agg@W1r^T + b1 + x@W1n^T); score1 ---------------
__global__ __launch_bounds__(256) void k_h1(const float* __restrict__ x,
    const float* __restrict__ agg12,
    const float* __restrict__ W1r, const float* __restrict__ b1,
    const float* __restrict__ W1n, const float* __restrict__ p1,
    float* __restrict__ h1, float* __restrict__ score1, int g0) {
  __shared__ float sWr[FIN * 64], sWn[FIN * 64], sb[64], sp[64];
  for (int i = threadIdx.x; i < 64 * FIN; i += 256) {
    int k = i / FIN, f = i % FIN;
    sWr[f * 64 + k] = W1r[i];     // transposed: conflict-free reads
    sWn[f * 64 + k] = W1n[i];
  }
  if (threadIdx.x < 64) { sb[threadIdx.x] = b1[threadIdx.x]; sp[threadIdx.x] = p1[threadIdx.x]; }
  __syncthreads();
  int lane = threadIdx.x & 63, wave = threadIdx.x >> 6;
  int s = blockIdx.x >> 8;                 // 256 blocks per graph, 16 nodes/block
  int nb = blockIdx.x & 255;
  int g = g0 + s;
  float pk = sp[lane];
  float nq = pk * pk;
#pragma unroll
  for (int o = 32; o; o >>= 1) nq += __shfl_xor(nq, o, 64);
  float inv_norm = 1.0f / sqrtf(nq);
  for (int jj = 0; jj < 4; jj++) {
    int node = (nb << 4) + (wave << 2) + jj;
    const float* ar = agg12 + ((size_t)s * NN + node) * FIN;
    const float* xr = x + ((size_t)g * NN + node) * FIN;
    float acc = sb[lane];
#pragma unroll
    for (int f = 0; f < FIN; f++)
      acc += ar[f] * sWr[f * 64 + lane] + xr[f] * sWn[f * 64 + lane];
    float h = fmaxf(acc, 0.f);
    h1[((size_t)s * NN + node) * HD + lane] = h;
    float v = h * pk;
#pragma unroll
    for (int o = 32; o; o >>= 1) v += __shfl_xor(v, o, 64);
    if (lane == 0) score1[(size_t)s * NN + node] = v * inv_norm;
  }
}

// ---------------- top-k select via in-LDS bitonic sort (jax.lax.top_k semantics)
__global__ __launch_bounds__(1024) void k_select(const float* __restrict__ score,
    int scStride, int nvalid, int K, int* __restrict__ sel, int selStride,
    int* __restrict__ pos, int posStride, float* __restrict__ tg) {
  __shared__ unsigned long long sk[4096];
  int s = blockIdx.x;
  const float* sc = score + (size_t)s * scStride;
  for (int i = threadIdx.x; i < 4096; i += 1024) {
    unsigned long long c = 0ull;
    if (i < nvalid) {
      unsigned int b = __float_as_uint(sc[i]);
      unsigned int key = (b & 0x80000000u) ? ~b : (b | 0x80000000u);  // order-preserving flip
      c = ((unsigned long long)key << 32) | (unsigned long long)(0xFFFFFFFFu - (unsigned int)i);
    }
    sk[i] = c;
  }
  __syncthreads();
  for (int k = 2; k <= 4096; k <<= 1) {
    for (int j = k >> 1; j > 0; j >>= 1) {
      for (int t = threadIdx.x; t < 2048; t += 1024) {
        int low = t & (j - 1);
        int i = ((t & ~(j - 1)) << 1) | low;
        int ix = i | j;
        bool down = ((i & k) == 0);       // overall descending
        unsigned long long A = sk[i], Bv = sk[ix];
        bool sw = down ? (A < Bv) : (A > Bv);
        if (sw) { sk[i] = Bv; sk[ix] = A; }
      }
      __syncthreads();
    }
  }
  for (int r = threadIdx.x; r < 4096; r += 1024) {
    if (r < nvalid) {
      int idx = (int)(0xFFFFFFFFu - (unsigned int)(sk[r] & 0xFFFFFFFFull));
      if (r < K) {
        sel[(size_t)s * selStride + r] = idx;
        if (pos) pos[(size_t)s * posStride + idx] = r;
        if (tg) tg[(size_t)s * selStride + r] = tanhf(sc[idx]);
      } else if (pos) {
        pos[(size_t)s * posStride + idx] = -1;
      }
    }
  }
}

// ---------------- conv2: wave per edge group; lane k handles feature k ------
__global__ __launch_bounds__(256) void k_conv2(const int* __restrict__ ei,
    const int* __restrict__ pos1, const int* __restrict__ sel1,
    const float* __restrict__ t1, const float* __restrict__ h1,
    float* __restrict__ agg64, int g0) {
  const int BPG = 128;
  int s = blockIdx.x / BPG;
  int w = ((blockIdx.x % BPG) << 2) + (threadIdx.x >> 6);
  int lane = threadIdx.x & 63;
  int g = g0 + s;
  const int* eg = ei + (size_t)g * 2 * EE;
  const int* P = pos1 + (size_t)s * NN;
  const int* S = sel1 + (size_t)s * KK1;
  const float* T = t1 + (size_t)s * KK1;
  const float* Hr = h1 + (size_t)s * NN * HD;
  float* A = agg64 + (size_t)s * KK1 * HD;
  const int EPW = EE / (BPG * 4);          // 64 edges per wave
  int e0 = w * EPW;
  for (int e = e0; e < e0 + EPW; e++) {
    int src = eg[e], dst = eg[EE + e];
    int ns = P[src], nd = P[dst];
    if ((ns | nd) >= 0) {
      float v = Hr[(size_t)S[ns] * HD + lane] * T[ns];
      atomicAdd(&A[(size_t)nd * HD + lane], v);
    }
  }
}

// ---------------- h2 = relu(agg64@W2r^T + b2 + h1k@W2n^T); score2 -----------
__global__ __launch_bounds__(256) void k_h2(const float* __restrict__ agg64,
    const float* __restrict__ h1, const int* __restrict__ sel1, const float* __restrict__ t1,
    const float* __restrict__ W2r, const float* __restrict__ b2,
    const float* __restrict__ W2n, const float* __restrict__ p2,
    float* __restrict__ h2, float* __restrict__ score2) {
  __shared__ float sWr[HD * HD], sWn[HD * HD], sb[64], sp[64];
  for (int i = threadIdx.x; i < HD * HD; i += 256) {
    int k = i >> 6, f = i & 63;
    sWr[f * 64 + k] = W2r[i];
    sWn[f * 64 + k] = W2n[i];
  }
  if (threadIdx.x < 64) { sb[threadIdx.x] = b2[threadIdx.x]; sp[threadIdx.x] = p2[threadIdx.x]; }
  __syncthreads();
  const int BPG = (KK1 + 15) / 16;         // 205
  int lane = threadIdx.x & 63, wave = threadIdx.x >> 6;
  int s = blockIdx.x / BPG;
  int jb = blockIdx.x % BPG;
  float pk = sp[lane];
  float nq = pk * pk;
#pragma unroll
  for (int o = 32; o; o >>= 1) nq += __shfl_xor(nq, o, 64);
  float inv_norm = 1.0f / sqrtf(nq);
  for (int jj = 0; jj < 4; jj++) {
    int j = jb * 16 + wave * 4 + jj;
    if (j >= KK1) break;
    const float* ar = agg64 + ((size_t)s * KK1 + j) * HD;
    int orig = sel1[(size_t)s * KK1 + j];
    float t = t1[(size_t)s * KK1 + j];
    const float* hr = h1 + ((size_t)s * NN + orig) * HD;
    float aR = 0.f, aN = 0.f;
#pragma unroll 8
    for (int f = 0; f < HD; f++) {
      aR += ar[f] * sWr[f * 64 + lane];
      aN += hr[f] * sWn[f * 64 + lane];
    }
    float h = fmaxf(sb[lane] + aR + aN * t, 0.f);
    h2[((size_t)s * KK1 + j) * HD + lane] = h;
    float v = h * pk;
#pragma unroll
    for (int o = 32; o; o >>= 1) v += __shfl_xor(v, o, 64);
    if (lane == 0) score2[(size_t)s * KK1 + j] = v * inv_norm;
  }
}

// ---------------- readout 1: x1 = [max || mean] of gated h1 over kept set ---
__global__ __launch_bounds__(256) void k_read1(const float* __restrict__ h1,
    const int* __restrict__ sel1, const float* __restrict__ t1, float* __restrict__ x1) {
  int s = blockIdx.x, k = threadIdx.x & 63, grp = threadIdx.x >> 6;
  float mx = -FLT_MAX, sm = 0.f;
  for (int r = grp; r < KK1; r += 4) {
    int orig = sel1[(size_t)s * KK1 + r];
    float v = h1[((size_t)s * NN + orig) * HD + k] * t1[(size_t)s * KK1 + r];
    mx = fmaxf(mx, v); sm += v;
  }
  __shared__ float smx[4][64], ssm[4][64];
  smx[grp][k] = mx; ssm[grp][k] = sm;
  __syncthreads();
  if (grp == 0) {
    for (int q = 1; q < 4; q++) { mx = fmaxf(mx, smx[q][k]); sm += ssm[q][k]; }
    x1[(size_t)s * 128 + k] = mx;
    x1[(size_t)s * 128 + 64 + k] = sm / (float)KK1;
  }
}

// ---------------- readout 2 + combine: feats = x1 + x2 ----------------------
__global__ __launch_bounds__(256) void k_read2(const float* __restrict__ h2,
    const int* __restrict__ sel2, const float* __restrict__ score2,
    const float* __restrict__ x1, float* __restrict__ feats, int g0) {
  int s = blockIdx.x, k = threadIdx.x & 63, grp = threadIdx.x >> 6;
  float mx = -FLT_MAX, sm = 0.f;
  for (int r = grp; r < KK2; r += 4) {
    int j = sel2[(size_t)s * KK2 + r];
    float v = h2[((size_t)s * KK1 + j) * HD + k] * tanhf(score2[(size_t)s * KK1 + j]);
    mx = fmaxf(mx, v); sm += v;
  }
  __shared__ float smx[4][64], ssm[4][64];
  smx[grp][k] = mx; ssm[grp][k] = sm;
  __syncthreads();
  if (grp == 0) {
    for (int q = 1; q < 4; q++) { mx = fmaxf(mx, smx[q][k]); sm += ssm[q][k]; }
    feats[(size_t)(g0 + s) * 128 + k] = x1[(size_t)s * 128 + k] + mx;
    feats[(size_t)(g0 + s) * 128 + 64 + k] = x1[(size_t)s * 128 + 64 + k] + sm / (float)KK2;
  }
}

// ---------------- head: MLP + softmax across graphs (axis 0) ----------------
__global__ __launch_bounds__(256) void k_head(const float* __restrict__ feats,
    const float* __restrict__ Wa1, const float* __restrict__ ba1,
    const float* __restrict__ Wa5, const float* __restrict__ ba5,
    float* __restrict__ out) {
  __shared__ float sF[BB * 128];
  __shared__ float sA1[BB * 64];
  __shared__ float sA5[BB * 10];
  for (int i = threadIdx.x; i < BB * 128; i += 256) sF[i] = feats[i];
  __syncthreads();
  for (int o = threadIdx.x; o < BB * 64; o += 256) {
    int b = o >> 6, j = o & 63;
    float acc = ba1[j];
    for (int i = 0; i < 128; i++) acc += sF[b * 128 + i] * Wa1[j * 128 + i];
    sA1[o] = fmaxf(acc, 0.f);
  }
  __syncthreads();
  for (int o = threadIdx.x; o < BB * 10; o += 256) {
    int b = o / 10, c = o % 10;
    float acc = ba5[c];
    for (int j = 0; j < 64; j++) acc += sA1[b * 64 + j] * Wa5[c * 64 + j];
    sA5[o] = acc;
  }
  __syncthreads();
  if (threadIdx.x < 10) {
    int c = threadIdx.x;
    float m = -FLT_MAX;
    for (int b = 0; b < BB; b++) m = fmaxf(m, sA5[b * 10 + c]);
    float sum = 0.f;
    for (int b = 0; b < BB; b++) sum += expf(sA5[b * 10 + c] - m);
    float inv = 1.0f / sum;
    for (int b = 0; b < BB; b++) out[b * 10 + c] = expf(sA5[b * 10 + c] - m) * inv;
  }
}

extern "C" void kernel_launch(void* const* d_in, const int* in_sizes, int n_in,
                              void* d_out, int out_size, void* d_ws, size_t ws_size,
                              hipStream_t stream) {
  const float* x   = (const float*)d_in[0];
  const int*   ei  = (const int*)d_in[1];
  const float* W1r = (const float*)d_in[2];
  const float* b1  = (const float*)d_in[3];
  const float* W1n = (const float*)d_in[4];
  const float* p1  = (const float*)d_in[5];
  const float* W2r = (const float*)d_in[6];
  const float* b2  = (const float*)d_in[7];
  const float* W2n = (const float*)d_in[8];
  const float* p2  = (const float*)d_in[9];
  const float* Wa1 = (const float*)d_in[10];
  const float* ba1 = (const float*)d_in[11];
  const float* Wa5 = (const float*)d_in[12];
  const float* ba5 = (const float*)d_in[13];
  float* out = (float*)d_out;

  char* base = (char*)d_ws;
  size_t off = 0;
  auto alloc = [&](size_t bytes) -> void* {
    void* p = base + off;
    off = (off + bytes + 255) & ~(size_t)255;
    return p;
  };
  float* feats = (float*)alloc((size_t)BB * 128 * 4);

  const size_t perSlot =
      ((size_t)NN * FIN + (size_t)NN * HD + NN + NN + KK1 + KK1 +
       (size_t)KK1 * HD + (size_t)KK1 * HD + KK1 + KK2 + 128) * 4 + 16 * 256;
  size_t avail = ws_size > off ? ws_size - off : 0;
  int CH = (int)(avail / perSlot);
  if (CH > BB) CH = BB;
  if (CH < 1) CH = 1;

  float* agg12  = (float*)alloc((size_t)CH * NN * FIN * 4);
  float* h1     = (float*)alloc((size_t)CH * NN * HD * 4);
  float* score1 = (float*)alloc((size_t)CH * NN * 4);
  int*   pos1   = (int*)alloc((size_t)CH * NN * 4);
  int*   sel1   = (int*)alloc((size_t)CH * KK1 * 4);
  float* t1     = (float*)alloc((size_t)CH * KK1 * 4);
  float* agg64  = (float*)alloc((size_t)CH * KK1 * HD * 4);
  float* h2     = (float*)alloc((size_t)CH * KK1 * HD * 4);
  float* score2 = (float*)alloc((size_t)CH * KK1 * 4);
  int*   sel2   = (int*)alloc((size_t)CH * KK2 * 4);
  float* x1     = (float*)alloc((size_t)CH * 128 * 4);

  for (int g0 = 0; g0 < BB; g0 += CH) {
    int G = (BB - g0) < CH ? (BB - g0) : CH;
    hipMemsetAsync(agg12, 0, (size_t)G * NN * FIN * 4, stream);
    hipMemsetAsync(agg64, 0, (size_t)G * KK1 * HD * 4, stream);
    k_conv1<<<G * 128, 256, 0, stream>>>(x, ei, agg12, g0);
    k_h1<<<G * 256, 256, 0, stream>>>(x, agg12, W1r, b1, W1n, p1, h1, score1, g0);
    k_select<<<G, 1024, 0, stream>>>(score1, NN, NN, KK1, sel1, KK1, pos1, NN, t1);
    k_conv2<<<G * 128, 256, 0, stream>>>(ei, pos1, sel1, t1, h1, agg64, g0);
    k_h2<<<G * 205, 256, 0, stream>>>(agg64, h1, sel1, t1, W2r, b2, W2n, p2, h2, score2);
    k_select<<<G, 1024, 0, stream>>>(score2, KK1, KK1, KK2, sel2, KK2, nullptr, 0, nullptr);
    k_read1<<<G, 256, 0, stream>>>(h1, sel1, t1, x1);
    k_read2<<<G, 256, 0, stream>>>(h2, sel2, score2, x1, feats, g0);
  }
  k_head<<<1, 256, 0, stream>>>(feats, Wa1, ba1, Wa5, ba5, out);
}

// Round 2
// 1661.673 us; speedup vs baseline: 1.7508x; 1.7508x over previous
//
#include <hip/hip_runtime.h>
#include <float.h>
#include <math.h>

#define BB 64
#define NN 4096
#define EE 32768
#define FIN 12
#define HD 64
#define KK1 3277
#define KK2 2622

// ---------- CSR build: per-graph counting sort of edges by dst --------------
// One block (1024 thr) per graph. Output: row_ofs[NN+1], esrc[EE] (src of each
// dst-sorted edge). LDS atomics only; no global atomics anywhere in the pipe.
__global__ __launch_bounds__(1024) void k_csr(const int* __restrict__ ei,
    int* __restrict__ row_ofs, int* __restrict__ esrc, int g0) {
  __shared__ int cnt[NN];
  __shared__ int part[1024];
  int s = blockIdx.x, g = g0 + s, t = threadIdx.x;
  const int* src = ei + (size_t)g * 2 * EE;
  const int* dst = src + EE;
  for (int i = t; i < NN; i += 1024) cnt[i] = 0;
  __syncthreads();
  for (int e = t; e < EE; e += 1024) atomicAdd(&cnt[dst[e]], 1);
  __syncthreads();
  // each thread owns 4 consecutive bins
  int c0 = cnt[t * 4], c1 = cnt[t * 4 + 1], c2 = cnt[t * 4 + 2], c3 = cnt[t * 4 + 3];
  int tot = c0 + c1 + c2 + c3;
  part[t] = tot;
  __syncthreads();
  for (int off = 1; off < 1024; off <<= 1) {   // Hillis-Steele inclusive scan
    int v = part[t];
    int add = (t >= off) ? part[t - off] : 0;
    __syncthreads();
    part[t] = v + add;
    __syncthreads();
  }
  int base = part[t] - tot;                    // exclusive prefix
  int b0 = base, b1 = base + c0, b2 = b1 + c1, b3 = b2 + c2;
  cnt[t * 4] = b0; cnt[t * 4 + 1] = b1; cnt[t * 4 + 2] = b2; cnt[t * 4 + 3] = b3;
  int* RO = row_ofs + (size_t)s * (NN + 1);
  RO[t * 4] = b0; RO[t * 4 + 1] = b1; RO[t * 4 + 2] = b2; RO[t * 4 + 3] = b3;
  if (t == 0) RO[NN] = EE;
  __syncthreads();
  int* ES = esrc + (size_t)s * EE;
  for (int e = t; e < EE; e += 1024) {
    int p = atomicAdd(&cnt[dst[e]], 1);
    ES[p] = src[e];
  }
}

// ---------- fused conv1: gather agg12 + h1 = relu(agg@W1r^T+b1+x@W1n^T) -----
__global__ __launch_bounds__(256) void k_h1f(const float* __restrict__ x,
    const int* __restrict__ row_ofs, const int* __restrict__ esrc,
    const float* __restrict__ W1r, const float* __restrict__ b1,
    const float* __restrict__ W1n, const float* __restrict__ p1,
    float* __restrict__ h1, float* __restrict__ score1, int g0) {
  __shared__ float sWr[FIN * 64], sWn[FIN * 64], sb[64], sp[64];
  for (int i = threadIdx.x; i < 64 * FIN; i += 256) {
    int k = i / FIN, f = i % FIN;
    sWr[f * 64 + k] = W1r[i];     // transposed: conflict-free reads
    sWn[f * 64 + k] = W1n[i];
  }
  if (threadIdx.x < 64) { sb[threadIdx.x] = b1[threadIdx.x]; sp[threadIdx.x] = p1[threadIdx.x]; }
  __syncthreads();
  int lane = threadIdx.x & 63, wave = threadIdx.x >> 6;
  int s = blockIdx.x >> 8;                 // 256 blocks per graph, 16 nodes/block
  int nb = blockIdx.x & 255;
  int g = g0 + s;
  float pk = sp[lane];
  float nq = pk * pk;
#pragma unroll
  for (int o = 32; o; o >>= 1) nq += __shfl_xor(nq, o, 64);
  float inv_norm = 1.0f / sqrtf(nq);
  const int* RO = row_ofs + (size_t)s * (NN + 1);
  const int* ES = esrc + (size_t)s * EE;
  const float* X = x + (size_t)g * NN * FIN;
  for (int jj = 0; jj < 4; jj++) {
    int node = (nb << 4) + (wave << 2) + jj;
    int r0 = RO[node], r1 = RO[node + 1];
    float af = 0.f, xf = 0.f;
    if (lane < FIN) {
      xf = X[(size_t)node * FIN + lane];
      for (int i = r0; i < r1; i++) af += X[(size_t)ES[i] * FIN + lane];
    }
    float acc = sb[lane];
#pragma unroll
    for (int f = 0; f < FIN; f++) {
      float a = __shfl(af, f, 64), xv = __shfl(xf, f, 64);
      acc += a * sWr[f * 64 + lane] + xv * sWn[f * 64 + lane];
    }
    float h = fmaxf(acc, 0.f);
    h1[((size_t)s * NN + node) * HD + lane] = h;
    float v = h * pk;
#pragma unroll
    for (int o = 32; o; o >>= 1) v += __shfl_xor(v, o, 64);
    if (lane == 0) score1[(size_t)s * NN + node] = v * inv_norm;
  }
}

// ---------- top-k select via in-LDS bitonic sort (jax.lax.top_k semantics) --
__global__ __launch_bounds__(1024) void k_select(const float* __restrict__ score,
    int scStride, int nvalid, int K, int* __restrict__ sel, int selStride,
    int* __restrict__ pos, int posStride, float* __restrict__ tg) {
  __shared__ unsigned long long sk[4096];
  int s = blockIdx.x;
  const float* sc = score + (size_t)s * scStride;
  for (int i = threadIdx.x; i < 4096; i += 1024) {
    unsigned long long c = 0ull;
    if (i < nvalid) {
      unsigned int b = __float_as_uint(sc[i]);
      unsigned int key = (b & 0x80000000u) ? ~b : (b | 0x80000000u);  // order-preserving flip
      c = ((unsigned long long)key << 32) | (unsigned long long)(0xFFFFFFFFu - (unsigned int)i);
    }
    sk[i] = c;
  }
  __syncthreads();
  for (int k = 2; k <= 4096; k <<= 1) {
    for (int j = k >> 1; j > 0; j >>= 1) {
      for (int t = threadIdx.x; t < 2048; t += 1024) {
        int low = t & (j - 1);
        int i = ((t & ~(j - 1)) << 1) | low;
        int ix = i | j;
        bool down = ((i & k) == 0);       // overall descending
        unsigned long long A = sk[i], Bv = sk[ix];
        bool sw = down ? (A < Bv) : (A > Bv);
        if (sw) { sk[i] = Bv; sk[ix] = A; }
      }
      __syncthreads();
    }
  }
  for (int r = threadIdx.x; r < 4096; r += 1024) {
    if (r < nvalid) {
      int idx = (int)(0xFFFFFFFFu - (unsigned int)(sk[r] & 0xFFFFFFFFull));
      if (r < K) {
        sel[(size_t)s * selStride + r] = idx;
        if (pos) pos[(size_t)s * posStride + idx] = r;
        if (tg) tg[(size_t)s * selStride + r] = tanhf(sc[idx]);
      } else if (pos) {
        pos[(size_t)s * posStride + idx] = -1;
      }
    }
  }
}

// ---------- fused conv2 + h2: gather agg64 via CSR, then W2 matmul + score --
__global__ __launch_bounds__(256) void k_c2h2(const int* __restrict__ row_ofs,
    const int* __restrict__ esrc, const int* __restrict__ pos1,
    const int* __restrict__ sel1, const float* __restrict__ t1,
    const float* __restrict__ h1,
    const float* __restrict__ W2r, const float* __restrict__ b2,
    const float* __restrict__ W2n, const float* __restrict__ p2,
    float* __restrict__ h2, float* __restrict__ score2) {
  __shared__ float sWr[HD * 64], sWn[HD * 64], sb[64], sp[64];
  __shared__ float sAgg[4][64], sHr[4][64];
  for (int i = threadIdx.x; i < HD * 64; i += 256) {
    int k = i >> 6, f = i & 63;
    sWr[f * 64 + k] = W2r[i];
    sWn[f * 64 + k] = W2n[i];
  }
  if (threadIdx.x < 64) { sb[threadIdx.x] = b2[threadIdx.x]; sp[threadIdx.x] = p2[threadIdx.x]; }
  __syncthreads();
  const int BPG = (KK1 + 15) / 16;         // 205 blocks per graph
  int lane = threadIdx.x & 63, wave = threadIdx.x >> 6;
  int s = blockIdx.x / BPG;
  int jb = blockIdx.x % BPG;
  float pk = sp[lane];
  float nq = pk * pk;
#pragma unroll
  for (int o = 32; o; o >>= 1) nq += __shfl_xor(nq, o, 64);
  float inv_norm = 1.0f / sqrtf(nq);
  const int* RO = row_ofs + (size_t)s * (NN + 1);
  const int* ES = esrc + (size_t)s * EE;
  const int* P = pos1 + (size_t)s * NN;
  const float* T = t1 + (size_t)s * KK1;
  const float* H = h1 + (size_t)s * NN * HD;
  for (int jj = 0; jj < 4; jj++) {
    int j = jb * 16 + wave * 4 + jj;
    bool valid = j < KK1;
    float t = 0.f;
    if (valid) {
      int d = sel1[(size_t)s * KK1 + j];
      t = T[j];
      int r0 = RO[d], r1 = RO[d + 1];
      float acc = 0.f;
      for (int i = r0; i < r1; i++) {
        int so = ES[i];
        int ns = P[so];
        if (ns >= 0) acc += H[(size_t)so * HD + lane] * T[ns];
      }
      sAgg[wave][lane] = acc;
      sHr[wave][lane] = H[(size_t)d * HD + lane];
    }
    __syncthreads();
    float aR = 0.f, aN = 0.f;
#pragma unroll 8
    for (int f = 0; f < HD; f++) {
      aR += sAgg[wave][f] * sWr[f * 64 + lane];
      aN += sHr[wave][f] * sWn[f * 64 + lane];
    }
    if (valid) {
      float h = fmaxf(sb[lane] + aR + aN * t, 0.f);
      h2[((size_t)s * KK1 + j) * HD + lane] = h;
      float v = h * pk;
#pragma unroll
      for (int o = 32; o; o >>= 1) v += __shfl_xor(v, o, 64);
      if (lane == 0) score2[(size_t)s * KK1 + j] = v * inv_norm;
    }
    __syncthreads();
  }
}

// ---------- readout 1: x1 = [max || mean] of gated h1 over kept set ---------
__global__ __launch_bounds__(256) void k_read1(const float* __restrict__ h1,
    const int* __restrict__ sel1, const float* __restrict__ t1, float* __restrict__ x1) {
  int s = blockIdx.x, k = threadIdx.x & 63, grp = threadIdx.x >> 6;
  float mx = -FLT_MAX, sm = 0.f;
  for (int r = grp; r < KK1; r += 4) {
    int orig = sel1[(size_t)s * KK1 + r];
    float v = h1[((size_t)s * NN + orig) * HD + k] * t1[(size_t)s * KK1 + r];
    mx = fmaxf(mx, v); sm += v;
  }
  __shared__ float smx[4][64], ssm[4][64];
  smx[grp][k] = mx; ssm[grp][k] = sm;
  __syncthreads();
  if (grp == 0) {
    for (int q = 1; q < 4; q++) { mx = fmaxf(mx, smx[q][k]); sm += ssm[q][k]; }
    x1[(size_t)s * 128 + k] = mx;
    x1[(size_t)s * 128 + 64 + k] = sm / (float)KK1;
  }
}

// ---------- readout 2 + combine: feats = x1 + x2 ----------------------------
__global__ __launch_bounds__(256) void k_read2(const float* __restrict__ h2,
    const int* __restrict__ sel2, const float* __restrict__ score2,
    const float* __restrict__ x1, float* __restrict__ feats, int g0) {
  int s = blockIdx.x, k = threadIdx.x & 63, grp = threadIdx.x >> 6;
  float mx = -FLT_MAX, sm = 0.f;
  for (int r = grp; r < KK2; r += 4) {
    int j = sel2[(size_t)s * KK2 + r];
    float v = h2[((size_t)s * KK1 + j) * HD + k] * tanhf(score2[(size_t)s * KK1 + j]);
    mx = fmaxf(mx, v); sm += v;
  }
  __shared__ float smx[4][64], ssm[4][64];
  smx[grp][k] = mx; ssm[grp][k] = sm;
  __syncthreads();
  if (grp == 0) {
    for (int q = 1; q < 4; q++) { mx = fmaxf(mx, smx[q][k]); sm += ssm[q][k]; }
    feats[(size_t)(g0 + s) * 128 + k] = x1[(size_t)s * 128 + k] + mx;
    feats[(size_t)(g0 + s) * 128 + 64 + k] = x1[(size_t)s * 128 + 64 + k] + sm / (float)KK2;
  }
}

// ---------- head: MLP + softmax across graphs (axis 0) ----------------------
__global__ __launch_bounds__(256) void k_head(const float* __restrict__ feats,
    const float* __restrict__ Wa1, const float* __restrict__ ba1,
    const float* __restrict__ Wa5, const float* __restrict__ ba5,
    float* __restrict__ out) {
  __shared__ float sF[BB * 128];
  __shared__ float sA1[BB * 64];
  __shared__ float sA5[BB * 10];
  for (int i = threadIdx.x; i < BB * 128; i += 256) sF[i] = feats[i];
  __syncthreads();
  for (int o = threadIdx.x; o < BB * 64; o += 256) {
    int b = o >> 6, j = o & 63;
    float acc = ba1[j];
    for (int i = 0; i < 128; i++) acc += sF[b * 128 + i] * Wa1[j * 128 + i];
    sA1[o] = fmaxf(acc, 0.f);
  }
  __syncthreads();
  for (int o = threadIdx.x; o < BB * 10; o += 256) {
    int b = o / 10, c = o % 10;
    float acc = ba5[c];
    for (int j = 0; j < 64; j++) acc += sA1[b * 64 + j] * Wa5[c * 64 + j];
    sA5[o] = acc;
  }
  __syncthreads();
  if (threadIdx.x < 10) {
    int c = threadIdx.x;
    float m = -FLT_MAX;
    for (int b = 0; b < BB; b++) m = fmaxf(m, sA5[b * 10 + c]);
    float sum = 0.f;
    for (int b = 0; b < BB; b++) sum += expf(sA5[b * 10 + c] - m);
    float inv = 1.0f / sum;
    for (int b = 0; b < BB; b++) out[b * 10 + c] = expf(sA5[b * 10 + c] - m) * inv;
  }
}

extern "C" void kernel_launch(void* const* d_in, const int* in_sizes, int n_in,
                              void* d_out, int out_size, void* d_ws, size_t ws_size,
                              hipStream_t stream) {
  const float* x   = (const float*)d_in[0];
  const int*   ei  = (const int*)d_in[1];
  const float* W1r = (const float*)d_in[2];
  const float* b1  = (const float*)d_in[3];
  const float* W1n = (const float*)d_in[4];
  const float* p1  = (const float*)d_in[5];
  const float* W2r = (const float*)d_in[6];
  const float* b2  = (const float*)d_in[7];
  const float* W2n = (const float*)d_in[8];
  const float* p2  = (const float*)d_in[9];
  const float* Wa1 = (const float*)d_in[10];
  const float* ba1 = (const float*)d_in[11];
  const float* Wa5 = (const float*)d_in[12];
  const float* ba5 = (const float*)d_in[13];
  float* out = (float*)d_out;

  char* base = (char*)d_ws;
  size_t off = 0;
  auto alloc = [&](size_t bytes) -> void* {
    void* p = base + off;
    off = (off + bytes + 255) & ~(size_t)255;
    return p;
  };
  float* feats = (float*)alloc((size_t)BB * 128 * 4);

  const size_t perSlot =
      ((size_t)(NN + 1) + EE + (size_t)NN * HD + NN + NN + KK1 + KK1 +
       (size_t)KK1 * HD + KK1 + KK2 + 128) * 4 + 16 * 256;
  size_t avail = ws_size > off ? ws_size - off : 0;
  int CH = (int)(avail / perSlot);
  if (CH > BB) CH = BB;
  if (CH < 1) CH = 1;

  int*   row_ofs = (int*)alloc((size_t)CH * (NN + 1) * 4);
  int*   esrc    = (int*)alloc((size_t)CH * EE * 4);
  float* h1      = (float*)alloc((size_t)CH * NN * HD * 4);
  float* score1  = (float*)alloc((size_t)CH * NN * 4);
  int*   pos1    = (int*)alloc((size_t)CH * NN * 4);
  int*   sel1    = (int*)alloc((size_t)CH * KK1 * 4);
  float* t1      = (float*)alloc((size_t)CH * KK1 * 4);
  float* h2      = (float*)alloc((size_t)CH * KK1 * HD * 4);
  float* score2  = (float*)alloc((size_t)CH * KK1 * 4);
  int*   sel2    = (int*)alloc((size_t)CH * KK2 * 4);
  float* x1      = (float*)alloc((size_t)CH * 128 * 4);

  for (int g0 = 0; g0 < BB; g0 += CH) {
    int G = (BB - g0) < CH ? (BB - g0) : CH;
    k_csr<<<G, 1024, 0, stream>>>(ei, row_ofs, esrc, g0);
    k_h1f<<<G * 256, 256, 0, stream>>>(x, row_ofs, esrc, W1r, b1, W1n, p1, h1, score1, g0);
    k_select<<<G, 1024, 0, stream>>>(score1, NN, NN, KK1, sel1, KK1, pos1, NN, t1);
    k_c2h2<<<G * 205, 256, 0, stream>>>(row_ofs, esrc, pos1, sel1, t1, h1,
                                        W2r, b2, W2n, p2, h2, score2);
    k_select<<<G, 1024, 0, stream>>>(score2, KK1, KK1, KK2, sel2, KK2, nullptr, 0, nullptr);
    k_read1<<<G, 256, 0, stream>>>(h1, sel1, t1, x1);
    k_read2<<<G, 256, 0, stream>>>(h2, sel2, score2, x1, feats, g0);
  }
  k_head<<<1, 256, 0, stream>>>(feats, Wa1, ba1, Wa5, ba5, out);
}

// Round 3
// 871.652 us; speedup vs baseline: 3.3376x; 1.9063x over previous
//
#include <hip/hip_runtime.h>
#include <float.h>
#include <math.h>

#define BB 64
#define NN 4096
#define EE 32768
#define FIN 12
#define HD 64
#define KK1 3277
#define KK2 2622
#define TB1 52   // ceil(KK1/64)

// ---------- CSR build: per-graph counting sort of edges by dst --------------
__global__ __launch_bounds__(1024) void k_csr(const int* __restrict__ ei,
    int* __restrict__ row_ofs, int* __restrict__ esrc, int g0) {
  __shared__ int cnt[NN];
  __shared__ int part[1024];
  int s = blockIdx.x, g = g0 + s, t = threadIdx.x;
  const int* src = ei + (size_t)g * 2 * EE;
  const int* dst = src + EE;
  for (int i = t; i < NN; i += 1024) cnt[i] = 0;
  __syncthreads();
  for (int e = t; e < EE; e += 1024) atomicAdd(&cnt[dst[e]], 1);
  __syncthreads();
  int c0 = cnt[t * 4], c1 = cnt[t * 4 + 1], c2 = cnt[t * 4 + 2], c3 = cnt[t * 4 + 3];
  int tot = c0 + c1 + c2 + c3;
  part[t] = tot;
  __syncthreads();
  for (int off = 1; off < 1024; off <<= 1) {
    int v = part[t];
    int add = (t >= off) ? part[t - off] : 0;
    __syncthreads();
    part[t] = v + add;
    __syncthreads();
  }
  int base = part[t] - tot;
  int b0 = base, b1 = base + c0, b2 = b1 + c1, b3 = b2 + c2;
  cnt[t * 4] = b0; cnt[t * 4 + 1] = b1; cnt[t * 4 + 2] = b2; cnt[t * 4 + 3] = b3;
  int* RO = row_ofs + (size_t)s * (NN + 1);
  RO[t * 4] = b0; RO[t * 4 + 1] = b1; RO[t * 4 + 2] = b2; RO[t * 4 + 3] = b3;
  if (t == 0) RO[NN] = EE;
  __syncthreads();
  int* ES = esrc + (size_t)s * EE;
  for (int e = t; e < EE; e += 1024) {
    int p = atomicAdd(&cnt[dst[e]], 1);
    ES[p] = src[e];
  }
}

// ---------- fused conv1: 4-wide parallel gather + h1 + score1 ---------------
__global__ __launch_bounds__(256) void k_h1f(const float* __restrict__ x,
    const int* __restrict__ row_ofs, const int* __restrict__ esrc,
    const float* __restrict__ W1r, const float* __restrict__ b1,
    const float* __restrict__ W1n, const float* __restrict__ p1,
    float* __restrict__ h1, float* __restrict__ score1, int g0) {
  __shared__ float sWr[FIN * 64], sWn[FIN * 64], sb[64], sp[64];
  for (int i = threadIdx.x; i < 64 * FIN; i += 256) {
    int k = i / FIN, f = i % FIN;
    sWr[f * 64 + k] = W1r[i];
    sWn[f * 64 + k] = W1n[i];
  }
  if (threadIdx.x < 64) { sb[threadIdx.x] = b1[threadIdx.x]; sp[threadIdx.x] = p1[threadIdx.x]; }
  __syncthreads();
  int lane = threadIdx.x & 63, wave = threadIdx.x >> 6;
  int sub = lane >> 4, fl = lane & 15;
  int s = blockIdx.x >> 8;
  int nb = blockIdx.x & 255;
  int g = g0 + s;
  float pk = sp[lane];
  float nq = pk * pk;
#pragma unroll
  for (int o = 32; o; o >>= 1) nq += __shfl_xor(nq, o, 64);
  float inv_norm = 1.0f / sqrtf(nq);
  const int* RO = row_ofs + (size_t)s * (NN + 1);
  const int* ES = esrc + (size_t)s * EE;
  const float* X = x + (size_t)g * NN * FIN;
  for (int jj = 0; jj < 4; jj++) {
    int node = (nb << 4) + (wave << 2) + jj;
    int r0 = RO[node], r1 = RO[node + 1];
    float af = 0.f, xf = 0.f;
    if (fl < FIN) xf = X[(size_t)node * FIN + fl];
    for (int i = r0 + sub; i < r1; i += 4) {
      int so = ES[i];
      if (fl < FIN) af += X[(size_t)so * FIN + fl];
    }
    af += __shfl_xor(af, 16, 64);
    af += __shfl_xor(af, 32, 64);
    float acc = sb[lane];
#pragma unroll
    for (int f = 0; f < FIN; f++) {
      float a = __shfl(af, f, 64), xv = __shfl(xf, f, 64);
      acc += a * sWr[f * 64 + lane] + xv * sWn[f * 64 + lane];
    }
    float h = fmaxf(acc, 0.f);
    h1[((size_t)s * NN + node) * HD + lane] = h;
    float v = h * pk;
#pragma unroll
    for (int o = 32; o; o >>= 1) v += __shfl_xor(v, o, 64);
    if (lane == 0) score1[(size_t)s * NN + node] = v * inv_norm;
  }
}

// ---------- top-k select via in-LDS bitonic sort ----------------------------
__global__ __launch_bounds__(1024) void k_select(const float* __restrict__ score,
    int scStride, int nvalid, int K, int* __restrict__ sel, int selStride,
    int* __restrict__ pos, int posStride, float* __restrict__ tg) {
  __shared__ unsigned long long sk[4096];
  int s = blockIdx.x;
  const float* sc = score + (size_t)s * scStride;
  for (int i = threadIdx.x; i < 4096; i += 1024) {
    unsigned long long c = 0ull;
    if (i < nvalid) {
      unsigned int b = __float_as_uint(sc[i]);
      unsigned int key = (b & 0x80000000u) ? ~b : (b | 0x80000000u);
      c = ((unsigned long long)key << 32) | (unsigned long long)(0xFFFFFFFFu - (unsigned int)i);
    }
    sk[i] = c;
  }
  __syncthreads();
  for (int k = 2; k <= 4096; k <<= 1) {
    for (int j = k >> 1; j > 0; j >>= 1) {
      for (int t = threadIdx.x; t < 2048; t += 1024) {
        int low = t & (j - 1);
        int i = ((t & ~(j - 1)) << 1) | low;
        int ix = i | j;
        bool down = ((i & k) == 0);
        unsigned long long A = sk[i], Bv = sk[ix];
        bool sw = down ? (A < Bv) : (A > Bv);
        if (sw) { sk[i] = Bv; sk[ix] = A; }
      }
      __syncthreads();
    }
  }
  for (int r = threadIdx.x; r < 4096; r += 1024) {
    if (r < nvalid) {
      int idx = (int)(0xFFFFFFFFu - (unsigned int)(sk[r] & 0xFFFFFFFFull));
      if (r < K) {
        sel[(size_t)s * selStride + r] = idx;
        if (pos) pos[(size_t)s * posStride + idx] = r;
        if (tg) tg[(size_t)s * selStride + r] = tanhf(sc[idx]);
      } else if (pos) {
        pos[(size_t)s * posStride + idx] = -1;
      }
    }
  }
}

// ---------- k_t2: Z = (t*h1[sel]) @ [W2r^T | W2n^T]; fused read1 partials ---
__global__ __launch_bounds__(256) void k_t2(const float* __restrict__ h1,
    const int* __restrict__ sel1, const float* __restrict__ t1,
    const float* __restrict__ W2r, const float* __restrict__ W2n,
    float* __restrict__ Zr, float* __restrict__ Zn,
    float* __restrict__ pmax, float* __restrict__ psum) {
  __shared__ float sW[64 * 128];       // sW[k*128 + c]: c<64 -> W2r, else W2n
  __shared__ float sG[64 * 68];        // padded stride 68
  __shared__ float redm[4][64], reds[4][64];
  int s = blockIdx.x / TB1;
  int tb = blockIdx.x % TB1;
  int j0 = tb * 64;
  int nv = KK1 - j0; if (nv > 64) nv = 64;
  int tid = threadIdx.x;
  for (int i = tid; i < 64 * 128; i += 256) {
    int k = i >> 7, c = i & 127;
    sW[i] = (c < 64) ? W2r[c * 64 + k] : W2n[(c - 64) * 64 + k];
  }
  {
    int r = tid >> 2, q = tid & 3;
    float4 v0 = {0.f,0.f,0.f,0.f}, v1 = v0, v2 = v0, v3 = v0;
    if (r < nv) {
      int j = j0 + r;
      int orig = sel1[(size_t)s * KK1 + j];
      float t = t1[(size_t)s * KK1 + j];
      const float4* hr = (const float4*)(h1 + ((size_t)s * NN + orig) * HD + q * 16);
      v0 = hr[0]; v1 = hr[1]; v2 = hr[2]; v3 = hr[3];
      v0.x *= t; v0.y *= t; v0.z *= t; v0.w *= t;
      v1.x *= t; v1.y *= t; v1.z *= t; v1.w *= t;
      v2.x *= t; v2.y *= t; v2.z *= t; v2.w *= t;
      v3.x *= t; v3.y *= t; v3.z *= t; v3.w *= t;
    }
    float* gw = &sG[r * 68 + q * 16];
    ((float4*)gw)[0] = v0; ((float4*)gw)[1] = v1;
    ((float4*)gw)[2] = v2; ((float4*)gw)[3] = v3;
  }
  __syncthreads();
  // fused readout-1 partials: per-col max/sum over valid rows
  {
    int c = tid & 63, qq = tid >> 6;
    float mx = -FLT_MAX, sm = 0.f;
    int rend = qq * 16 + 16; if (rend > nv) rend = nv;
    for (int rr = qq * 16; rr < rend; rr++) {
      float v = sG[rr * 68 + c];
      mx = fmaxf(mx, v); sm += v;
    }
    redm[qq][c] = mx; reds[qq][c] = sm;
  }
  __syncthreads();
  if (tid < 64) {
    float mx = redm[0][tid], sm = reds[0][tid];
    for (int qq = 1; qq < 4; qq++) { mx = fmaxf(mx, redm[qq][tid]); sm += reds[qq][tid]; }
    pmax[((size_t)s * TB1 + tb) * 64 + tid] = mx;
    psum[((size_t)s * TB1 + tb) * 64 + tid] = sm;
  }
  // GEMM: 8 rows x 4 cols per thread
  int rg = tid >> 5;
  int c0 = (tid & 31) * 4;
  float acc[8][4];
#pragma unroll
  for (int i = 0; i < 8; i++)
#pragma unroll
    for (int cc = 0; cc < 4; cc++) acc[i][cc] = 0.f;
  for (int k = 0; k < 64; k += 4) {
    float4 w0 = *(const float4*)&sW[(k + 0) * 128 + c0];
    float4 w1 = *(const float4*)&sW[(k + 1) * 128 + c0];
    float4 w2 = *(const float4*)&sW[(k + 2) * 128 + c0];
    float4 w3 = *(const float4*)&sW[(k + 3) * 128 + c0];
#pragma unroll
    for (int i = 0; i < 8; i++) {
      float4 g = *(const float4*)&sG[(rg * 8 + i) * 68 + k];
      acc[i][0] += g.x * w0.x + g.y * w1.x + g.z * w2.x + g.w * w3.x;
      acc[i][1] += g.x * w0.y + g.y * w1.y + g.z * w2.y + g.w * w3.y;
      acc[i][2] += g.x * w0.z + g.y * w1.z + g.z * w2.z + g.w * w3.z;
      acc[i][3] += g.x * w0.w + g.y * w1.w + g.z * w2.w + g.w * w3.w;
    }
  }
#pragma unroll
  for (int i = 0; i < 8; i++) {
    int j = j0 + rg * 8 + i;
    if (j < KK1) {
      float4 v = {acc[i][0], acc[i][1], acc[i][2], acc[i][3]};
      if (c0 < 64) *(float4*)&Zr[((size_t)s * KK1 + j) * 64 + c0] = v;
      else         *(float4*)&Zn[((size_t)s * KK1 + j) * 64 + (c0 - 64)] = v;
    }
  }
}

// ---------- k_agg2: h2 = relu(b2 + Zn[j] + sum_{kept j'->j} Zr[j']); score2 -
__global__ __launch_bounds__(256) void k_agg2(const int* __restrict__ row_ofs,
    const int* __restrict__ esrc, const int* __restrict__ pos1,
    const int* __restrict__ sel1, const float* __restrict__ Zr,
    const float* __restrict__ Zn, const float* __restrict__ b2,
    const float* __restrict__ p2, float* __restrict__ h2,
    float* __restrict__ score2) {
  const int BPG = (KK1 + 3) / 4;  // 820
  int s = blockIdx.x / BPG;
  int j = (blockIdx.x % BPG) * 4 + (threadIdx.x >> 6);
  int lane = threadIdx.x & 63;
  float pk = p2[lane];
  float nq = pk * pk;
#pragma unroll
  for (int o = 32; o; o >>= 1) nq += __shfl_xor(nq, o, 64);
  float inv_norm = 1.0f / sqrtf(nq);
  if (j >= KK1) return;
  const int* RO = row_ofs + (size_t)s * (NN + 1);
  const int* ES = esrc + (size_t)s * EE;
  const int* P  = pos1 + (size_t)s * NN;
  int d = sel1[(size_t)s * KK1 + j];
  int r0 = RO[d], r1 = RO[d + 1];
  float acc = b2[lane] + Zn[((size_t)s * KK1 + j) * 64 + lane];
  const float* ZRb = Zr + (size_t)s * KK1 * 64;
  for (int base = r0; base < r1; base += 64) {
    int n = r1 - base; if (n > 64) n = 64;
    int srow = -1;
    if (base + lane < r1) srow = P[ES[base + lane]];
    for (int i = 0; i < n; i++) {
      int sr = __shfl(srow, i, 64);
      if (sr >= 0) acc += ZRb[(size_t)sr * 64 + lane];
    }
  }
  float h = fmaxf(acc, 0.f);
  h2[((size_t)s * KK1 + j) * 64 + lane] = h;
  float v = h * pk;
#pragma unroll
  for (int o = 32; o; o >>= 1) v += __shfl_xor(v, o, 64);
  if (lane == 0) score2[(size_t)s * KK1 + j] = v * inv_norm;
}

// ---------- read1 final reduce over k_t2 partials ---------------------------
__global__ __launch_bounds__(64) void k_read1r(const float* __restrict__ pmax,
    const float* __restrict__ psum, float* __restrict__ x1) {
  int s = blockIdx.x, k = threadIdx.x;
  float mx = -FLT_MAX, sm = 0.f;
  for (int t = 0; t < TB1; t++) {
    mx = fmaxf(mx, pmax[((size_t)s * TB1 + t) * 64 + k]);
    sm += psum[((size_t)s * TB1 + t) * 64 + k];
  }
  x1[(size_t)s * 128 + k] = mx;
  x1[(size_t)s * 128 + 64 + k] = sm / (float)KK1;
}

// ---------- readout 2 + combine: feats = x1 + x2 ----------------------------
__global__ __launch_bounds__(256) void k_read2(const float* __restrict__ h2,
    const int* __restrict__ sel2, const float* __restrict__ score2,
    const float* __restrict__ x1, float* __restrict__ feats, int g0) {
  int s = blockIdx.x, k = threadIdx.x & 63, grp = threadIdx.x >> 6;
  float mx = -FLT_MAX, sm = 0.f;
  for (int r = grp; r < KK2; r += 4) {
    int j = sel2[(size_t)s * KK2 + r];
    float v = h2[((size_t)s * KK1 + j) * HD + k] * tanhf(score2[(size_t)s * KK1 + j]);
    mx = fmaxf(mx, v); sm += v;
  }
  __shared__ float smx[4][64], ssm[4][64];
  smx[grp][k] = mx; ssm[grp][k] = sm;
  __syncthreads();
  if (grp == 0) {
    for (int q = 1; q < 4; q++) { mx = fmaxf(mx, smx[q][k]); sm += ssm[q][k]; }
    feats[(size_t)(g0 + s) * 128 + k] = x1[(size_t)s * 128 + k] + mx;
    feats[(size_t)(g0 + s) * 128 + 64 + k] = x1[(size_t)s * 128 + 64 + k] + sm / (float)KK2;
  }
}

// ---------- head: MLP + softmax across graphs (axis 0) ----------------------
__global__ __launch_bounds__(256) void k_head(const float* __restrict__ feats,
    const float* __restrict__ Wa1, const float* __restrict__ ba1,
    const float* __restrict__ Wa5, const float* __restrict__ ba5,
    float* __restrict__ out) {
  __shared__ float sF[BB * 128];
  __shared__ float sA1[BB * 64];
  __shared__ float sA5[BB * 10];
  for (int i = threadIdx.x; i < BB * 128; i += 256) sF[i] = feats[i];
  __syncthreads();
  for (int o = threadIdx.x; o < BB * 64; o += 256) {
    int b = o >> 6, j = o & 63;
    float acc = ba1[j];
    for (int i = 0; i < 128; i++) acc += sF[b * 128 + i] * Wa1[j * 128 + i];
    sA1[o] = fmaxf(acc, 0.f);
  }
  __syncthreads();
  for (int o = threadIdx.x; o < BB * 10; o += 256) {
    int b = o / 10, c = o % 10;
    float acc = ba5[c];
    for (int j = 0; j < 64; j++) acc += sA1[b * 64 + j] * Wa5[c * 64 + j];
    sA5[o] = acc;
  }
  __syncthreads();
  if (threadIdx.x < 10) {
    int c = threadIdx.x;
    float m = -FLT_MAX;
    for (int b = 0; b < BB; b++) m = fmaxf(m, sA5[b * 10 + c]);
    float sum = 0.f;
    for (int b = 0; b < BB; b++) sum += expf(sA5[b * 10 + c] - m);
    float inv = 1.0f / sum;
    for (int b = 0; b < BB; b++) out[b * 10 + c] = expf(sA5[b * 10 + c] - m) * inv;
  }
}

extern "C" void kernel_launch(void* const* d_in, const int* in_sizes, int n_in,
                              void* d_out, int out_size, void* d_ws, size_t ws_size,
                              hipStream_t stream) {
  const float* x   = (const float*)d_in[0];
  const int*   ei  = (const int*)d_in[1];
  const float* W1r = (const float*)d_in[2];
  const float* b1  = (const float*)d_in[3];
  const float* W1n = (const float*)d_in[4];
  const float* p1  = (const float*)d_in[5];
  const float* W2r = (const float*)d_in[6];
  const float* b2  = (const float*)d_in[7];
  const float* W2n = (const float*)d_in[8];
  const float* p2  = (const float*)d_in[9];
  const float* Wa1 = (const float*)d_in[10];
  const float* ba1 = (const float*)d_in[11];
  const float* Wa5 = (const float*)d_in[12];
  const float* ba5 = (const float*)d_in[13];
  float* out = (float*)d_out;

  char* base = (char*)d_ws;
  size_t off = 0;
  auto alloc = [&](size_t bytes) -> void* {
    void* p = base + off;
    off = (off + bytes + 255) & ~(size_t)255;
    return p;
  };
  float* feats = (float*)alloc((size_t)BB * 128 * 4);

  const size_t perSlot =
      ((size_t)(NN + 1) + EE + (size_t)NN * HD + NN + NN + KK1 + KK1 +
       3 * (size_t)KK1 * HD + KK1 + KK2 + 2 * (size_t)TB1 * 64 + 128) * 4 + 20 * 256;
  size_t avail = ws_size > off ? ws_size - off : 0;
  int CH = (int)(avail / perSlot);
  if (CH > BB) CH = BB;
  if (CH < 1) CH = 1;

  int*   row_ofs = (int*)alloc((size_t)CH * (NN + 1) * 4);
  int*   esrc    = (int*)alloc((size_t)CH * EE * 4);
  float* h1      = (float*)alloc((size_t)CH * NN * HD * 4);
  float* score1  = (float*)alloc((size_t)CH * NN * 4);
  int*   pos1    = (int*)alloc((size_t)CH * NN * 4);
  int*   sel1    = (int*)alloc((size_t)CH * KK1 * 4);
  float* t1      = (float*)alloc((size_t)CH * KK1 * 4);
  float* Zr      = (float*)alloc((size_t)CH * KK1 * HD * 4);
  float* Zn      = (float*)alloc((size_t)CH * KK1 * HD * 4);
  float* h2      = (float*)alloc((size_t)CH * KK1 * HD * 4);
  float* score2  = (float*)alloc((size_t)CH * KK1 * 4);
  int*   sel2    = (int*)alloc((size_t)CH * KK2 * 4);
  float* pmax    = (float*)alloc((size_t)CH * TB1 * 64 * 4);
  float* psum    = (float*)alloc((size_t)CH * TB1 * 64 * 4);
  float* x1      = (float*)alloc((size_t)CH * 128 * 4);

  for (int g0 = 0; g0 < BB; g0 += CH) {
    int G = (BB - g0) < CH ? (BB - g0) : CH;
    k_csr<<<G, 1024, 0, stream>>>(ei, row_ofs, esrc, g0);
    k_h1f<<<G * 256, 256, 0, stream>>>(x, row_ofs, esrc, W1r, b1, W1n, p1, h1, score1, g0);
    k_select<<<G, 1024, 0, stream>>>(score1, NN, NN, KK1, sel1, KK1, pos1, NN, t1);
    k_t2<<<G * TB1, 256, 0, stream>>>(h1, sel1, t1, W2r, W2n, Zr, Zn, pmax, psum);
    k_agg2<<<G * 820, 256, 0, stream>>>(row_ofs, esrc, pos1, sel1, Zr, Zn, b2, p2, h2, score2);
    k_select<<<G, 1024, 0, stream>>>(score2, KK1, KK1, KK2, sel2, KK2, nullptr, 0, nullptr);
    k_read1r<<<G, 64, 0, stream>>>(pmax, psum, x1);
    k_read2<<<G, 256, 0, stream>>>(h2, sel2, score2, x1, feats, g0);
  }
  k_head<<<1, 256, 0, stream>>>(feats, Wa1, ba1, Wa5, ba5, out);
}

// Round 4
// 591.309 us; speedup vs baseline: 4.9199x; 1.4741x over previous
//
#include <hip/hip_runtime.h>
#include <float.h>
#include <math.h>

#define BB 64
#define NN 4096
#define EE 32768
#define FIN 12
#define HD 64
#define KK1 3277
#define KK2 2622
#define TB1 52   // ceil(KK1/64)
#define RB2 16   // blocks per graph for read2 partials

// ---------- CSR build: per-graph counting sort of edges by dst --------------
__global__ __launch_bounds__(1024) void k_csr(const int* __restrict__ ei,
    int* __restrict__ row_ofs, int* __restrict__ esrc, int g0) {
  __shared__ int cnt[NN];
  __shared__ int part[1024];
  int s = blockIdx.x, g = g0 + s, t = threadIdx.x;
  const int* src = ei + (size_t)g * 2 * EE;
  const int* dst = src + EE;
  for (int i = t; i < NN; i += 1024) cnt[i] = 0;
  __syncthreads();
  for (int e = t; e < EE; e += 1024) atomicAdd(&cnt[dst[e]], 1);
  __syncthreads();
  int c0 = cnt[t * 4], c1 = cnt[t * 4 + 1], c2 = cnt[t * 4 + 2], c3 = cnt[t * 4 + 3];
  int tot = c0 + c1 + c2 + c3;
  part[t] = tot;
  __syncthreads();
  for (int off = 1; off < 1024; off <<= 1) {
    int v = part[t];
    int add = (t >= off) ? part[t - off] : 0;
    __syncthreads();
    part[t] = v + add;
    __syncthreads();
  }
  int base = part[t] - tot;
  int b0 = base, b1 = base + c0, b2 = b1 + c1, b3 = b2 + c2;
  cnt[t * 4] = b0; cnt[t * 4 + 1] = b1; cnt[t * 4 + 2] = b2; cnt[t * 4 + 3] = b3;
  int* RO = row_ofs + (size_t)s * (NN + 1);
  RO[t * 4] = b0; RO[t * 4 + 1] = b1; RO[t * 4 + 2] = b2; RO[t * 4 + 3] = b3;
  if (t == 0) RO[NN] = EE;
  __syncthreads();
  int* ES = esrc + (size_t)s * EE;
  for (int e = t; e < EE; e += 1024) {
    int p = atomicAdd(&cnt[dst[e]], 1);
    ES[p] = src[e];
  }
}

// ---------- fused conv1: 4-wide parallel gather + h1 + score1 ---------------
__global__ __launch_bounds__(256) void k_h1f(const float* __restrict__ x,
    const int* __restrict__ row_ofs, const int* __restrict__ esrc,
    const float* __restrict__ W1r, const float* __restrict__ b1,
    const float* __restrict__ W1n, const float* __restrict__ p1,
    float* __restrict__ h1, float* __restrict__ score1, int g0) {
  __shared__ float sWr[FIN * 64], sWn[FIN * 64], sb[64], sp[64];
  for (int i = threadIdx.x; i < 64 * FIN; i += 256) {
    int k = i / FIN, f = i % FIN;
    sWr[f * 64 + k] = W1r[i];
    sWn[f * 64 + k] = W1n[i];
  }
  if (threadIdx.x < 64) { sb[threadIdx.x] = b1[threadIdx.x]; sp[threadIdx.x] = p1[threadIdx.x]; }
  __syncthreads();
  int lane = threadIdx.x & 63, wave = threadIdx.x >> 6;
  int sub = lane >> 4, fl = lane & 15;
  int s = blockIdx.x >> 8;
  int nb = blockIdx.x & 255;
  int g = g0 + s;
  float pk = sp[lane];
  float nq = pk * pk;
#pragma unroll
  for (int o = 32; o; o >>= 1) nq += __shfl_xor(nq, o, 64);
  float inv_norm = 1.0f / sqrtf(nq);
  const int* RO = row_ofs + (size_t)s * (NN + 1);
  const int* ES = esrc + (size_t)s * EE;
  const float* X = x + (size_t)g * NN * FIN;
  for (int jj = 0; jj < 4; jj++) {
    int node = (nb << 4) + (wave << 2) + jj;
    int r0 = RO[node], r1 = RO[node + 1];
    float af = 0.f, xf = 0.f;
    if (fl < FIN) xf = X[(size_t)node * FIN + fl];
    for (int i = r0 + sub; i < r1; i += 4) {
      int so = ES[i];
      if (fl < FIN) af += X[(size_t)so * FIN + fl];
    }
    af += __shfl_xor(af, 16, 64);
    af += __shfl_xor(af, 32, 64);
    float acc = sb[lane];
#pragma unroll
    for (int f = 0; f < FIN; f++) {
      float a = __shfl(af, f, 64), xv = __shfl(xf, f, 64);
      acc += a * sWr[f * 64 + lane] + xv * sWn[f * 64 + lane];
    }
    float h = fmaxf(acc, 0.f);
    h1[((size_t)s * NN + node) * HD + lane] = h;
    float v = h * pk;
#pragma unroll
    for (int o = 32; o; o >>= 1) v += __shfl_xor(v, o, 64);
    if (lane == 0) score1[(size_t)s * NN + node] = v * inv_norm;
  }
}

// ---------- top-k select via in-LDS bitonic sort ----------------------------
__global__ __launch_bounds__(1024) void k_select(const float* __restrict__ score,
    int scStride, int nvalid, int K, int* __restrict__ sel, int selStride,
    int* __restrict__ pos, int posStride, float* __restrict__ tg) {
  __shared__ unsigned long long sk[4096];
  int s = blockIdx.x;
  const float* sc = score + (size_t)s * scStride;
  for (int i = threadIdx.x; i < 4096; i += 1024) {
    unsigned long long c = 0ull;
    if (i < nvalid) {
      unsigned int b = __float_as_uint(sc[i]);
      unsigned int key = (b & 0x80000000u) ? ~b : (b | 0x80000000u);
      c = ((unsigned long long)key << 32) | (unsigned long long)(0xFFFFFFFFu - (unsigned int)i);
    }
    sk[i] = c;
  }
  __syncthreads();
  for (int k = 2; k <= 4096; k <<= 1) {
    for (int j = k >> 1; j > 0; j >>= 1) {
      for (int t = threadIdx.x; t < 2048; t += 1024) {
        int low = t & (j - 1);
        int i = ((t & ~(j - 1)) << 1) | low;
        int ix = i | j;
        bool down = ((i & k) == 0);
        unsigned long long A = sk[i], Bv = sk[ix];
        bool sw = down ? (A < Bv) : (A > Bv);
        if (sw) { sk[i] = Bv; sk[ix] = A; }
      }
      __syncthreads();
    }
  }
  for (int r = threadIdx.x; r < 4096; r += 1024) {
    if (r < nvalid) {
      int idx = (int)(0xFFFFFFFFu - (unsigned int)(sk[r] & 0xFFFFFFFFull));
      if (r < K) {
        if (sel) sel[(size_t)s * selStride + r] = idx;
        if (pos) pos[(size_t)s * posStride + idx] = r;
        if (tg) tg[(size_t)s * selStride + r] = tanhf(sc[idx]);
      } else if (pos) {
        pos[(size_t)s * posStride + idx] = -1;
      }
    }
  }
}

// ---------- k_t2: Z = (t*h1[sel]) @ [W2r^T | W2n^T]; fused read1 partials ---
__global__ __launch_bounds__(256) void k_t2(const float* __restrict__ h1,
    const int* __restrict__ sel1, const float* __restrict__ t1,
    const float* __restrict__ W2r, const float* __restrict__ W2n,
    float* __restrict__ Zr, float* __restrict__ Zn,
    float* __restrict__ pmax, float* __restrict__ psum) {
  __shared__ float sW[64 * 128];       // sW[k*128 + c]: c<64 -> W2r, else W2n
  __shared__ float sG[64 * 68];        // padded stride 68
  __shared__ float redm[4][64], reds[4][64];
  int s = blockIdx.x / TB1;
  int tb = blockIdx.x % TB1;
  int j0 = tb * 64;
  int nv = KK1 - j0; if (nv > 64) nv = 64;
  int tid = threadIdx.x;
  for (int i = tid; i < 64 * 128; i += 256) {
    int k = i >> 7, c = i & 127;
    sW[i] = (c < 64) ? W2r[c * 64 + k] : W2n[(c - 64) * 64 + k];
  }
  {
    int r = tid >> 2, q = tid & 3;
    float4 v0 = {0.f,0.f,0.f,0.f}, v1 = v0, v2 = v0, v3 = v0;
    if (r < nv) {
      int j = j0 + r;
      int orig = sel1[(size_t)s * KK1 + j];
      float t = t1[(size_t)s * KK1 + j];
      const float4* hr = (const float4*)(h1 + ((size_t)s * NN + orig) * HD + q * 16);
      v0 = hr[0]; v1 = hr[1]; v2 = hr[2]; v3 = hr[3];
      v0.x *= t; v0.y *= t; v0.z *= t; v0.w *= t;
      v1.x *= t; v1.y *= t; v1.z *= t; v1.w *= t;
      v2.x *= t; v2.y *= t; v2.z *= t; v2.w *= t;
      v3.x *= t; v3.y *= t; v3.z *= t; v3.w *= t;
    }
    float* gw = &sG[r * 68 + q * 16];
    ((float4*)gw)[0] = v0; ((float4*)gw)[1] = v1;
    ((float4*)gw)[2] = v2; ((float4*)gw)[3] = v3;
  }
  __syncthreads();
  {
    int c = tid & 63, qq = tid >> 6;
    float mx = -FLT_MAX, sm = 0.f;
    int rend = qq * 16 + 16; if (rend > nv) rend = nv;
    for (int rr = qq * 16; rr < rend; rr++) {
      float v = sG[rr * 68 + c];
      mx = fmaxf(mx, v); sm += v;
    }
    redm[qq][c] = mx; reds[qq][c] = sm;
  }
  __syncthreads();
  if (tid < 64) {
    float mx = redm[0][tid], sm = reds[0][tid];
    for (int qq = 1; qq < 4; qq++) { mx = fmaxf(mx, redm[qq][tid]); sm += reds[qq][tid]; }
    pmax[((size_t)s * TB1 + tb) * 64 + tid] = mx;
    psum[((size_t)s * TB1 + tb) * 64 + tid] = sm;
  }
  int rg = tid >> 5;
  int c0 = (tid & 31) * 4;
  float acc[8][4];
#pragma unroll
  for (int i = 0; i < 8; i++)
#pragma unroll
    for (int cc = 0; cc < 4; cc++) acc[i][cc] = 0.f;
  for (int k = 0; k < 64; k += 4) {
    float4 w0 = *(const float4*)&sW[(k + 0) * 128 + c0];
    float4 w1 = *(const float4*)&sW[(k + 1) * 128 + c0];
    float4 w2 = *(const float4*)&sW[(k + 2) * 128 + c0];
    float4 w3 = *(const float4*)&sW[(k + 3) * 128 + c0];
#pragma unroll
    for (int i = 0; i < 8; i++) {
      float4 g = *(const float4*)&sG[(rg * 8 + i) * 68 + k];
      acc[i][0] += g.x * w0.x + g.y * w1.x + g.z * w2.x + g.w * w3.x;
      acc[i][1] += g.x * w0.y + g.y * w1.y + g.z * w2.y + g.w * w3.y;
      acc[i][2] += g.x * w0.z + g.y * w1.z + g.z * w2.z + g.w * w3.z;
      acc[i][3] += g.x * w0.w + g.y * w1.w + g.z * w2.w + g.w * w3.w;
    }
  }
#pragma unroll
  for (int i = 0; i < 8; i++) {
    int j = j0 + rg * 8 + i;
    if (j < KK1) {
      float4 v = {acc[i][0], acc[i][1], acc[i][2], acc[i][3]};
      if (c0 < 64) *(float4*)&Zr[((size_t)s * KK1 + j) * 64 + c0] = v;
      else         *(float4*)&Zn[((size_t)s * KK1 + j) * 64 + (c0 - 64)] = v;
    }
  }
}

// ---------- k_agg2: h2 = relu(b2 + Zn[j] + sum_{kept j'->j} Zr[j']); score2 -
__global__ __launch_bounds__(256) void k_agg2(const int* __restrict__ row_ofs,
    const int* __restrict__ esrc, const int* __restrict__ pos1,
    const int* __restrict__ sel1, const float* __restrict__ Zr,
    const float* __restrict__ Zn, const float* __restrict__ b2,
    const float* __restrict__ p2, float* __restrict__ h2,
    float* __restrict__ score2) {
  const int BPG = (KK1 + 3) / 4;  // 820
  int s = blockIdx.x / BPG;
  int j = (blockIdx.x % BPG) * 4 + (threadIdx.x >> 6);
  int lane = threadIdx.x & 63;
  float pk = p2[lane];
  float nq = pk * pk;
#pragma unroll
  for (int o = 32; o; o >>= 1) nq += __shfl_xor(nq, o, 64);
  float inv_norm = 1.0f / sqrtf(nq);
  if (j >= KK1) return;
  const int* RO = row_ofs + (size_t)s * (NN + 1);
  const int* ES = esrc + (size_t)s * EE;
  const int* P  = pos1 + (size_t)s * NN;
  int d = sel1[(size_t)s * KK1 + j];
  int r0 = RO[d], r1 = RO[d + 1];
  float acc = b2[lane] + Zn[((size_t)s * KK1 + j) * 64 + lane];
  const float* ZRb = Zr + (size_t)s * KK1 * 64;
  for (int base = r0; base < r1; base += 64) {
    int n = r1 - base; if (n > 64) n = 64;
    int srow = -1;
    if (base + lane < r1) srow = P[ES[base + lane]];
    for (int i = 0; i < n; i++) {
      int sr = __shfl(srow, i, 64);
      if (sr >= 0) acc += ZRb[(size_t)sr * 64 + lane];
    }
  }
  float h = fmaxf(acc, 0.f);
  h2[((size_t)s * KK1 + j) * 64 + lane] = h;
  float v = h * pk;
#pragma unroll
  for (int o = 32; o; o >>= 1) v += __shfl_xor(v, o, 64);
  if (lane == 0) score2[(size_t)s * KK1 + j] = v * inv_norm;
}

// ---------- read1 final reduce over k_t2 partials ---------------------------
__global__ __launch_bounds__(64) void k_read1r(const float* __restrict__ pmax,
    const float* __restrict__ psum, float* __restrict__ x1) {
  int s = blockIdx.x, k = threadIdx.x;
  float mx = -FLT_MAX, sm = 0.f;
  for (int t = 0; t < TB1; t++) {
    mx = fmaxf(mx, pmax[((size_t)s * TB1 + t) * 64 + k]);
    sm += psum[((size_t)s * TB1 + t) * 64 + k];
  }
  x1[(size_t)s * 128 + k] = mx;
  x1[(size_t)s * 128 + 64 + k] = sm / (float)KK1;
}

// ---------- read2 partials: stream h2 rows, mask by pos2 --------------------
__global__ __launch_bounds__(256) void k_read2p(const float* __restrict__ h2,
    const int* __restrict__ pos2, const float* __restrict__ score2,
    float* __restrict__ p2max, float* __restrict__ p2sum) {
  int s = blockIdx.x / RB2, pb = blockIdx.x % RB2;
  int lane = threadIdx.x & 63, wave = threadIdx.x >> 6;
  const int ROWS = (KK1 + RB2 - 1) / RB2;  // 205
  int j0 = pb * ROWS;
  int j1 = j0 + ROWS; if (j1 > KK1) j1 = KK1;
  float mx = -FLT_MAX, sm = 0.f;
  for (int j = j0 + wave; j < j1; j += 4) {
    if (pos2[(size_t)s * KK1 + j] >= 0) {
      float t = tanhf(score2[(size_t)s * KK1 + j]);
      float v = h2[((size_t)s * KK1 + j) * HD + lane] * t;
      mx = fmaxf(mx, v); sm += v;
    }
  }
  __shared__ float smx[4][64], ssm[4][64];
  smx[wave][lane] = mx; ssm[wave][lane] = sm;
  __syncthreads();
  if (wave == 0) {
    for (int q = 1; q < 4; q++) { mx = fmaxf(mx, smx[q][lane]); sm += ssm[q][lane]; }
    p2max[((size_t)s * RB2 + pb) * 64 + lane] = mx;
    p2sum[((size_t)s * RB2 + pb) * 64 + lane] = sm;
  }
}

// ---------- read2 final reduce + combine: feats = x1 + x2 -------------------
__global__ __launch_bounds__(64) void k_read2r(const float* __restrict__ p2max,
    const float* __restrict__ p2sum, const float* __restrict__ x1,
    float* __restrict__ feats, int g0) {
  int s = blockIdx.x, k = threadIdx.x;
  float mx = -FLT_MAX, sm = 0.f;
  for (int t = 0; t < RB2; t++) {
    mx = fmaxf(mx, p2max[((size_t)s * RB2 + t) * 64 + k]);
    sm += p2sum[((size_t)s * RB2 + t) * 64 + k];
  }
  feats[(size_t)(g0 + s) * 128 + k] = x1[(size_t)s * 128 + k] + mx;
  feats[(size_t)(g0 + s) * 128 + 64 + k] = x1[(size_t)s * 128 + 64 + k] + sm / (float)KK2;
}

// ---------- head: MLP + softmax across graphs (axis 0) ----------------------
__global__ __launch_bounds__(256) void k_head(const float* __restrict__ feats,
    const float* __restrict__ Wa1, const float* __restrict__ ba1,
    const float* __restrict__ Wa5, const float* __restrict__ ba5,
    float* __restrict__ out) {
  __shared__ float sF[BB * 128];
  __shared__ float sA1[BB * 64];
  __shared__ float sA5[BB * 10];
  for (int i = threadIdx.x; i < BB * 128; i += 256) sF[i] = feats[i];
  __syncthreads();
  for (int o = threadIdx.x; o < BB * 64; o += 256) {
    int b = o >> 6, j = o & 63;
    float acc = ba1[j];
    for (int i = 0; i < 128; i++) acc += sF[b * 128 + i] * Wa1[j * 128 + i];
    sA1[o] = fmaxf(acc, 0.f);
  }
  __syncthreads();
  for (int o = threadIdx.x; o < BB * 10; o += 256) {
    int b = o / 10, c = o % 10;
    float acc = ba5[c];
    for (int j = 0; j < 64; j++) acc += sA1[b * 64 + j] * Wa5[c * 64 + j];
    sA5[o] = acc;
  }
  __syncthreads();
  if (threadIdx.x < 10) {
    int c = threadIdx.x;
    float m = -FLT_MAX;
    for (int b = 0; b < BB; b++) m = fmaxf(m, sA5[b * 10 + c]);
    float sum = 0.f;
    for (int b = 0; b < BB; b++) sum += expf(sA5[b * 10 + c] - m);
    float inv = 1.0f / sum;
    for (int b = 0; b < BB; b++) out[b * 10 + c] = expf(sA5[b * 10 + c] - m) * inv;
  }
}

extern "C" void kernel_launch(void* const* d_in, const int* in_sizes, int n_in,
                              void* d_out, int out_size, void* d_ws, size_t ws_size,
                              hipStream_t stream) {
  const float* x   = (const float*)d_in[0];
  const int*   ei  = (const int*)d_in[1];
  const float* W1r = (const float*)d_in[2];
  const float* b1  = (const float*)d_in[3];
  const float* W1n = (const float*)d_in[4];
  const float* p1  = (const float*)d_in[5];
  const float* W2r = (const float*)d_in[6];
  const float* b2  = (const float*)d_in[7];
  const float* W2n = (const float*)d_in[8];
  const float* p2  = (const float*)d_in[9];
  const float* Wa1 = (const float*)d_in[10];
  const float* ba1 = (const float*)d_in[11];
  const float* Wa5 = (const float*)d_in[12];
  const float* ba5 = (const float*)d_in[13];
  float* out = (float*)d_out;

  char* base = (char*)d_ws;
  size_t off = 0;
  auto alloc = [&](size_t bytes) -> void* {
    void* p = base + off;
    off = (off + bytes + 255) & ~(size_t)255;
    return p;
  };
  float* feats = (float*)alloc((size_t)BB * 128 * 4);

  const size_t perSlot =
      ((size_t)(NN + 1) + EE + (size_t)NN * HD + NN + NN + 2 * (size_t)KK1 + KK1 +
       3 * (size_t)KK1 * HD + KK1 + 2 * (size_t)TB1 * 64 + 2 * (size_t)RB2 * 64 + 128) * 4
      + 24 * 256;
  size_t avail = ws_size > off ? ws_size - off : 0;
  int CH = (int)(avail / perSlot);
  if (CH > BB) CH = BB;
  if (CH < 1) CH = 1;

  int*   row_ofs = (int*)alloc((size_t)CH * (NN + 1) * 4);
  int*   esrc    = (int*)alloc((size_t)CH * EE * 4);
  float* h1      = (float*)alloc((size_t)CH * NN * HD * 4);
  float* score1  = (float*)alloc((size_t)CH * NN * 4);
  int*   pos1    = (int*)alloc((size_t)CH * NN * 4);
  int*   sel1    = (int*)alloc((size_t)CH * KK1 * 4);
  float* t1      = (float*)alloc((size_t)CH * KK1 * 4);
  float* Zr      = (float*)alloc((size_t)CH * KK1 * HD * 4);
  float* Zn      = (float*)alloc((size_t)CH * KK1 * HD * 4);
  float* h2      = (float*)alloc((size_t)CH * KK1 * HD * 4);
  float* score2  = (float*)alloc((size_t)CH * KK1 * 4);
  int*   pos2    = (int*)alloc((size_t)CH * KK1 * 4);
  float* pmax    = (float*)alloc((size_t)CH * TB1 * 64 * 4);
  float* psum    = (float*)alloc((size_t)CH * TB1 * 64 * 4);
  float* p2max   = (float*)alloc((size_t)CH * RB2 * 64 * 4);
  float* p2sum   = (float*)alloc((size_t)CH * RB2 * 64 * 4);
  float* x1      = (float*)alloc((size_t)CH * 128 * 4);

  for (int g0 = 0; g0 < BB; g0 += CH) {
    int G = (BB - g0) < CH ? (BB - g0) : CH;
    k_csr<<<G, 1024, 0, stream>>>(ei, row_ofs, esrc, g0);
    k_h1f<<<G * 256, 256, 0, stream>>>(x, row_ofs, esrc, W1r, b1, W1n, p1, h1, score1, g0);
    k_select<<<G, 1024, 0, stream>>>(score1, NN, NN, KK1, sel1, KK1, pos1, NN, t1);
    k_t2<<<G * TB1, 256, 0, stream>>>(h1, sel1, t1, W2r, W2n, Zr, Zn, pmax, psum);
    k_agg2<<<G * 820, 256, 0, stream>>>(row_ofs, esrc, pos1, sel1, Zr, Zn, b2, p2, h2, score2);
    k_select<<<G, 1024, 0, stream>>>(score2, KK1, KK1, KK2, nullptr, 0, pos2, KK1, nullptr);
    k_read1r<<<G, 64, 0, stream>>>(pmax, psum, x1);
    k_read2p<<<G * RB2, 256, 0, stream>>>(h2, pos2, score2, p2max, p2sum);
    k_read2r<<<G, 64, 0, stream>>>(p2max, p2sum, x1, feats, g0);
  }
  k_head<<<1, 256, 0, stream>>>(feats, Wa1, ba1, Wa5, ba5, out);
}

// Round 5
// 550.236 us; speedup vs baseline: 5.2872x; 1.0746x over previous
//
#include <hip/hip_runtime.h>
#include <float.h>
#include <math.h>

#define BB 64
#define NN 4096
#define EE 32768
#define FIN 12
#define HD 64
#define KK1 3277
#define KK2 2622
#define TB1 52   // ceil(KK1/64)
#define RB2 16   // blocks per graph for read2 partials
#define BPG2 820 // blocks per graph for agg2 (4 rows/block)

// ---------- CSR build: per-graph counting sort of edges by dst --------------
__global__ __launch_bounds__(1024) void k_csr(const int* __restrict__ ei,
    int* __restrict__ row_ofs, int* __restrict__ esrc, int g0) {
  __shared__ int cnt[NN];
  __shared__ int part[1024];
  int s = blockIdx.x, g = g0 + s, t = threadIdx.x;
  const int* src = ei + (size_t)g * 2 * EE;
  const int* dst = src + EE;
  for (int i = t; i < NN; i += 1024) cnt[i] = 0;
  __syncthreads();
  for (int e = t; e < EE; e += 1024) atomicAdd(&cnt[dst[e]], 1);
  __syncthreads();
  int c0 = cnt[t * 4], c1 = cnt[t * 4 + 1], c2 = cnt[t * 4 + 2], c3 = cnt[t * 4 + 3];
  int tot = c0 + c1 + c2 + c3;
  part[t] = tot;
  __syncthreads();
  for (int off = 1; off < 1024; off <<= 1) {
    int v = part[t];
    int add = (t >= off) ? part[t - off] : 0;
    __syncthreads();
    part[t] = v + add;
    __syncthreads();
  }
  int base = part[t] - tot;
  int b0 = base, b1 = base + c0, b2 = b1 + c1, b3 = b2 + c2;
  cnt[t * 4] = b0; cnt[t * 4 + 1] = b1; cnt[t * 4 + 2] = b2; cnt[t * 4 + 3] = b3;
  int* RO = row_ofs + (size_t)s * (NN + 1);
  RO[t * 4] = b0; RO[t * 4 + 1] = b1; RO[t * 4 + 2] = b2; RO[t * 4 + 3] = b3;
  if (t == 0) RO[NN] = EE;
  __syncthreads();
  int* ES = esrc + (size_t)s * EE;
  for (int e = t; e < EE; e += 1024) {
    int p = atomicAdd(&cnt[dst[e]], 1);
    ES[p] = src[e];
  }
}

// ---------- fused conv1: 4-wide parallel gather + h1 + score1 ---------------
__global__ __launch_bounds__(256) void k_h1f(const float* __restrict__ x,
    const int* __restrict__ row_ofs, const int* __restrict__ esrc,
    const float* __restrict__ W1r, const float* __restrict__ b1,
    const float* __restrict__ W1n, const float* __restrict__ p1,
    float* __restrict__ h1, float* __restrict__ score1, int g0) {
  __shared__ float sWr[FIN * 64], sWn[FIN * 64], sb[64], sp[64];
  for (int i = threadIdx.x; i < 64 * FIN; i += 256) {
    int k = i / FIN, f = i % FIN;
    sWr[f * 64 + k] = W1r[i];
    sWn[f * 64 + k] = W1n[i];
  }
  if (threadIdx.x < 64) { sb[threadIdx.x] = b1[threadIdx.x]; sp[threadIdx.x] = p1[threadIdx.x]; }
  __syncthreads();
  int lane = threadIdx.x & 63, wave = threadIdx.x >> 6;
  int sub = lane >> 4, fl = lane & 15;
  int s = blockIdx.x >> 8;
  int nb = blockIdx.x & 255;
  int g = g0 + s;
  float pk = sp[lane];
  float nq = pk * pk;
#pragma unroll
  for (int o = 32; o; o >>= 1) nq += __shfl_xor(nq, o, 64);
  float inv_norm = 1.0f / sqrtf(nq);
  const int* RO = row_ofs + (size_t)s * (NN + 1);
  const int* ES = esrc + (size_t)s * EE;
  const float* X = x + (size_t)g * NN * FIN;
  for (int jj = 0; jj < 4; jj++) {
    int node = (nb << 4) + (wave << 2) + jj;
    int r0 = RO[node], r1 = RO[node + 1];
    float af = 0.f, xf = 0.f;
    if (fl < FIN) xf = X[(size_t)node * FIN + fl];
    for (int i = r0 + sub; i < r1; i += 4) {
      int so = ES[i];
      if (fl < FIN) af += X[(size_t)so * FIN + fl];
    }
    af += __shfl_xor(af, 16, 64);
    af += __shfl_xor(af, 32, 64);
    float acc = sb[lane];
#pragma unroll
    for (int f = 0; f < FIN; f++) {
      float a = __shfl(af, f, 64), xv = __shfl(xf, f, 64);
      acc += a * sWr[f * 64 + lane] + xv * sWn[f * 64 + lane];
    }
    float h = fmaxf(acc, 0.f);
    h1[((size_t)s * NN + node) * HD + lane] = h;
    float v = h * pk;
#pragma unroll
    for (int o = 32; o; o >>= 1) v += __shfl_xor(v, o, 64);
    if (lane == 0) score1[(size_t)s * NN + node] = v * inv_norm;
  }
}

// ---------- top-k select via in-LDS bitonic sort ----------------------------
// Stage 1: also zeroes Zr rows of DROPPED nodes (zr != nullptr).
__global__ __launch_bounds__(1024) void k_select(const float* __restrict__ score,
    int scStride, int nvalid, int K, int* __restrict__ sel, int selStride,
    int* __restrict__ pos, int posStride, float* __restrict__ tg,
    float* __restrict__ zr) {
  __shared__ unsigned long long sk[4096];
  int s = blockIdx.x;
  const float* sc = score + (size_t)s * scStride;
  for (int i = threadIdx.x; i < 4096; i += 1024) {
    unsigned long long c = 0ull;
    if (i < nvalid) {
      unsigned int b = __float_as_uint(sc[i]);
      unsigned int key = (b & 0x80000000u) ? ~b : (b | 0x80000000u);
      c = ((unsigned long long)key << 32) | (unsigned long long)(0xFFFFFFFFu - (unsigned int)i);
    }
    sk[i] = c;
  }
  __syncthreads();
  for (int k = 2; k <= 4096; k <<= 1) {
    for (int j = k >> 1; j > 0; j >>= 1) {
      for (int t = threadIdx.x; t < 2048; t += 1024) {
        int low = t & (j - 1);
        int i = ((t & ~(j - 1)) << 1) | low;
        int ix = i | j;
        bool down = ((i & k) == 0);
        unsigned long long A = sk[i], Bv = sk[ix];
        bool sw = down ? (A < Bv) : (A > Bv);
        if (sw) { sk[i] = Bv; sk[ix] = A; }
      }
      __syncthreads();
    }
  }
  for (int r = threadIdx.x; r < 4096; r += 1024) {
    if (r < nvalid) {
      int idx = (int)(0xFFFFFFFFu - (unsigned int)(sk[r] & 0xFFFFFFFFull));
      if (r < K) {
        if (sel) sel[(size_t)s * selStride + r] = idx;
        if (pos) pos[(size_t)s * posStride + idx] = r;
        if (tg) tg[(size_t)s * selStride + r] = tanhf(sc[idx]);
      } else {
        if (pos) pos[(size_t)s * posStride + idx] = -1;
        if (zr) {
          float4* zp = (float4*)(zr + ((size_t)s * NN + idx) * 64);
#pragma unroll
          for (int q = 0; q < 16; q++) zp[q] = make_float4(0.f, 0.f, 0.f, 0.f);
        }
      }
    }
  }
}

// ---------- k_t2: Z = (t*h1[sel]) @ [W2r^T | W2n^T]; fused read1 partials ---
// Zr is ORIG-indexed (NN rows/graph, dropped rows pre-zeroed by k_select).
__global__ __launch_bounds__(256) void k_t2(const float* __restrict__ h1,
    const int* __restrict__ sel1, const float* __restrict__ t1,
    const float* __restrict__ W2r, const float* __restrict__ W2n,
    float* __restrict__ Zr, float* __restrict__ Zn,
    float* __restrict__ pmax, float* __restrict__ psum) {
  __shared__ float sW[64 * 128];       // sW[k*128 + c]: c<64 -> W2r, else W2n
  __shared__ float sG[64 * 68];        // padded stride 68
  __shared__ float redm[4][64], reds[4][64];
  __shared__ int sOrig[64];
  int s = blockIdx.x / TB1;
  int tb = blockIdx.x % TB1;
  int j0 = tb * 64;
  int nv = KK1 - j0; if (nv > 64) nv = 64;
  int tid = threadIdx.x;
  for (int i = tid; i < 64 * 128; i += 256) {
    int k = i >> 7, c = i & 127;
    sW[i] = (c < 64) ? W2r[c * 64 + k] : W2n[(c - 64) * 64 + k];
  }
  {
    int r = tid >> 2, q = tid & 3;
    float4 v0 = {0.f,0.f,0.f,0.f}, v1 = v0, v2 = v0, v3 = v0;
    if (r < nv) {
      int j = j0 + r;
      int orig = sel1[(size_t)s * KK1 + j];
      if (q == 0) sOrig[r] = orig;
      float t = t1[(size_t)s * KK1 + j];
      const float4* hr = (const float4*)(h1 + ((size_t)s * NN + orig) * HD + q * 16);
      v0 = hr[0]; v1 = hr[1]; v2 = hr[2]; v3 = hr[3];
      v0.x *= t; v0.y *= t; v0.z *= t; v0.w *= t;
      v1.x *= t; v1.y *= t; v1.z *= t; v1.w *= t;
      v2.x *= t; v2.y *= t; v2.z *= t; v2.w *= t;
      v3.x *= t; v3.y *= t; v3.z *= t; v3.w *= t;
    }
    float* gw = &sG[r * 68 + q * 16];
    ((float4*)gw)[0] = v0; ((float4*)gw)[1] = v1;
    ((float4*)gw)[2] = v2; ((float4*)gw)[3] = v3;
  }
  __syncthreads();
  {
    int c = tid & 63, qq = tid >> 6;
    float mx = -FLT_MAX, sm = 0.f;
    int rend = qq * 16 + 16; if (rend > nv) rend = nv;
    for (int rr = qq * 16; rr < rend; rr++) {
      float v = sG[rr * 68 + c];
      mx = fmaxf(mx, v); sm += v;
    }
    redm[qq][c] = mx; reds[qq][c] = sm;
  }
  __syncthreads();
  if (tid < 64) {
    float mx = redm[0][tid], sm = reds[0][tid];
    for (int qq = 1; qq < 4; qq++) { mx = fmaxf(mx, redm[qq][tid]); sm += reds[qq][tid]; }
    pmax[((size_t)s * TB1 + tb) * 64 + tid] = mx;
    psum[((size_t)s * TB1 + tb) * 64 + tid] = sm;
  }
  int rg = tid >> 5;
  int c0 = (tid & 31) * 4;
  float acc[8][4];
#pragma unroll
  for (int i = 0; i < 8; i++)
#pragma unroll
    for (int cc = 0; cc < 4; cc++) acc[i][cc] = 0.f;
  for (int k = 0; k < 64; k += 4) {
    float4 w0 = *(const float4*)&sW[(k + 0) * 128 + c0];
    float4 w1 = *(const float4*)&sW[(k + 1) * 128 + c0];
    float4 w2 = *(const float4*)&sW[(k + 2) * 128 + c0];
    float4 w3 = *(const float4*)&sW[(k + 3) * 128 + c0];
#pragma unroll
    for (int i = 0; i < 8; i++) {
      float4 g = *(const float4*)&sG[(rg * 8 + i) * 68 + k];
      acc[i][0] += g.x * w0.x + g.y * w1.x + g.z * w2.x + g.w * w3.x;
      acc[i][1] += g.x * w0.y + g.y * w1.y + g.z * w2.y + g.w * w3.y;
      acc[i][2] += g.x * w0.z + g.y * w1.z + g.z * w2.z + g.w * w3.z;
      acc[i][3] += g.x * w0.w + g.y * w1.w + g.z * w2.w + g.w * w3.w;
    }
  }
#pragma unroll
  for (int i = 0; i < 8; i++) {
    int j = j0 + rg * 8 + i;
    if (j < KK1) {
      float4 v = {acc[i][0], acc[i][1], acc[i][2], acc[i][3]};
      if (c0 < 64) *(float4*)&Zr[((size_t)s * NN + sOrig[rg * 8 + i]) * 64 + c0] = v;
      else         *(float4*)&Zn[((size_t)s * KK1 + j) * 64 + (c0 - 64)] = v;
    }
  }
}

// ---------- k_agg2: h2 = relu(b2 + Zn[j] + sum_{e: dst=d} Zr[src]); score2 --
// Branchless: Zr rows of dropped srcs are zero. XCD-affinity swizzle.
__global__ __launch_bounds__(256) void k_agg2(const int* __restrict__ row_ofs,
    const int* __restrict__ esrc, const int* __restrict__ sel1,
    const float* __restrict__ Zr, const float* __restrict__ Zn,
    const float* __restrict__ b2, const float* __restrict__ p2,
    float* __restrict__ h2, float* __restrict__ score2, int G8) {
  int b = blockIdx.x;
  int s, jb;
  if (G8 > 0) {                 // all blocks of graph s land on XCD s/G8
    int hi = b >> 3;
    s = (b & 7) * G8 + hi / BPG2;
    jb = hi % BPG2;
  } else { s = b / BPG2; jb = b % BPG2; }
  int j = jb * 4 + (threadIdx.x >> 6);
  int lane = threadIdx.x & 63;
  float pk = p2[lane];
  float nq = pk * pk;
#pragma unroll
  for (int o = 32; o; o >>= 1) nq += __shfl_xor(nq, o, 64);
  float inv_norm = 1.0f / sqrtf(nq);
  if (j >= KK1) return;
  const int* RO = row_ofs + (size_t)s * (NN + 1);
  const int* ES = esrc + (size_t)s * EE;
  int d = sel1[(size_t)s * KK1 + j];
  int r0 = RO[d], r1 = RO[d + 1];
  float acc = b2[lane] + Zn[((size_t)s * KK1 + j) * 64 + lane];
  float a0 = 0.f, a1 = 0.f, a2 = 0.f, a3 = 0.f;
  const float* ZRb = Zr + (size_t)s * NN * 64;
  for (int base = r0; base < r1; base += 64) {
    int n = r1 - base; if (n > 64) n = 64;
    int srow = 0;
    if (base + lane < r1) srow = ES[base + lane];
    int i = 0;
    for (; i + 4 <= n; i += 4) {
      int s0 = __shfl(srow, i, 64),     s1 = __shfl(srow, i + 1, 64);
      int s2 = __shfl(srow, i + 2, 64), s3 = __shfl(srow, i + 3, 64);
      a0 += ZRb[(size_t)s0 * 64 + lane];
      a1 += ZRb[(size_t)s1 * 64 + lane];
      a2 += ZRb[(size_t)s2 * 64 + lane];
      a3 += ZRb[(size_t)s3 * 64 + lane];
    }
    for (; i < n; i++) acc += ZRb[(size_t)__shfl(srow, i, 64) * 64 + lane];
  }
  acc += (a0 + a1) + (a2 + a3);
  float h = fmaxf(acc, 0.f);
  h2[((size_t)s * KK1 + j) * 64 + lane] = h;
  float v = h * pk;
#pragma unroll
  for (int o = 32; o; o >>= 1) v += __shfl_xor(v, o, 64);
  if (lane == 0) score2[(size_t)s * KK1 + j] = v * inv_norm;
}

// ---------- read1 final reduce over k_t2 partials ---------------------------
__global__ __launch_bounds__(64) void k_read1r(const float* __restrict__ pmax,
    const float* __restrict__ psum, float* __restrict__ x1) {
  int s = blockIdx.x, k = threadIdx.x;
  float mx = -FLT_MAX, sm = 0.f;
  for (int t = 0; t < TB1; t++) {
    mx = fmaxf(mx, pmax[((size_t)s * TB1 + t) * 64 + k]);
    sm += psum[((size_t)s * TB1 + t) * 64 + k];
  }
  x1[(size_t)s * 128 + k] = mx;
  x1[(size_t)s * 128 + 64 + k] = sm / (float)KK1;
}

// ---------- read2 partials: stream h2 rows, mask by pos2 --------------------
__global__ __launch_bounds__(256) void k_read2p(const float* __restrict__ h2,
    const int* __restrict__ pos2, const float* __restrict__ score2,
    float* __restrict__ p2max, float* __restrict__ p2sum) {
  int s = blockIdx.x / RB2, pb = blockIdx.x % RB2;
  int lane = threadIdx.x & 63, wave = threadIdx.x >> 6;
  const int ROWS = (KK1 + RB2 - 1) / RB2;  // 205
  int j0 = pb * ROWS;
  int j1 = j0 + ROWS; if (j1 > KK1) j1 = KK1;
  float mx = -FLT_MAX, sm = 0.f;
  for (int j = j0 + wave; j < j1; j += 4) {
    if (pos2[(size_t)s * KK1 + j] >= 0) {
      float t = tanhf(score2[(size_t)s * KK1 + j]);
      float v = h2[((size_t)s * KK1 + j) * HD + lane] * t;
      mx = fmaxf(mx, v); sm += v;
    }
  }
  __shared__ float smx[4][64], ssm[4][64];
  smx[wave][lane] = mx; ssm[wave][lane] = sm;
  __syncthreads();
  if (wave == 0) {
    for (int q = 1; q < 4; q++) { mx = fmaxf(mx, smx[q][lane]); sm += ssm[q][lane]; }
    p2max[((size_t)s * RB2 + pb) * 64 + lane] = mx;
    p2sum[((size_t)s * RB2 + pb) * 64 + lane] = sm;
  }
}

// ---------- read2 final reduce + combine: feats = x1 + x2 -------------------
__global__ __launch_bounds__(64) void k_read2r(const float* __restrict__ p2max,
    const float* __restrict__ p2sum, const float* __restrict__ x1,
    float* __restrict__ feats, int g0) {
  int s = blockIdx.x, k = threadIdx.x;
  float mx = -FLT_MAX, sm = 0.f;
  for (int t = 0; t < RB2; t++) {
    mx = fmaxf(mx, p2max[((size_t)s * RB2 + t) * 64 + k]);
    sm += p2sum[((size_t)s * RB2 + t) * 64 + k];
  }
  feats[(size_t)(g0 + s) * 128 + k] = x1[(size_t)s * 128 + k] + mx;
  feats[(size_t)(g0 + s) * 128 + 64 + k] = x1[(size_t)s * 128 + 64 + k] + sm / (float)KK2;
}

// ---------- head: MLP + softmax across graphs (axis 0) ----------------------
__global__ __launch_bounds__(256) void k_head(const float* __restrict__ feats,
    const float* __restrict__ Wa1, const float* __restrict__ ba1,
    const float* __restrict__ Wa5, const float* __restrict__ ba5,
    float* __restrict__ out) {
  __shared__ float sF[BB * 128];
  __shared__ float sA1[BB * 64];
  __shared__ float sA5[BB * 10];
  for (int i = threadIdx.x; i < BB * 128; i += 256) sF[i] = feats[i];
  __syncthreads();
  for (int o = threadIdx.x; o < BB * 64; o += 256) {
    int b = o >> 6, j = o & 63;
    float acc = ba1[j];
    for (int i = 0; i < 128; i++) acc += sF[b * 128 + i] * Wa1[j * 128 + i];
    sA1[o] = fmaxf(acc, 0.f);
  }
  __syncthreads();
  for (int o = threadIdx.x; o < BB * 10; o += 256) {
    int b = o / 10, c = o % 10;
    float acc = ba5[c];
    for (int j = 0; j < 64; j++) acc += sA1[b * 64 + j] * Wa5[c * 64 + j];
    sA5[o] = acc;
  }
  __syncthreads();
  if (threadIdx.x < 10) {
    int c = threadIdx.x;
    float m = -FLT_MAX;
    for (int b = 0; b < BB; b++) m = fmaxf(m, sA5[b * 10 + c]);
    float sum = 0.f;
    for (int b = 0; b < BB; b++) sum += expf(sA5[b * 10 + c] - m);
    float inv = 1.0f / sum;
    for (int b = 0; b < BB; b++) out[b * 10 + c] = expf(sA5[b * 10 + c] - m) * inv;
  }
}

extern "C" void kernel_launch(void* const* d_in, const int* in_sizes, int n_in,
                              void* d_out, int out_size, void* d_ws, size_t ws_size,
                              hipStream_t stream) {
  const float* x   = (const float*)d_in[0];
  const int*   ei  = (const int*)d_in[1];
  const float* W1r = (const float*)d_in[2];
  const float* b1  = (const float*)d_in[3];
  const float* W1n = (const float*)d_in[4];
  const float* p1  = (const float*)d_in[5];
  const float* W2r = (const float*)d_in[6];
  const float* b2  = (const float*)d_in[7];
  const float* W2n = (const float*)d_in[8];
  const float* p2  = (const float*)d_in[9];
  const float* Wa1 = (const float*)d_in[10];
  const float* ba1 = (const float*)d_in[11];
  const float* Wa5 = (const float*)d_in[12];
  const float* ba5 = (const float*)d_in[13];
  float* out = (float*)d_out;

  char* base = (char*)d_ws;
  size_t off = 0;
  auto alloc = [&](size_t bytes) -> void* {
    void* p = base + off;
    off = (off + bytes + 255) & ~(size_t)255;
    return p;
  };
  float* feats = (float*)alloc((size_t)BB * 128 * 4);

  const size_t perSlot =
      ((size_t)(NN + 1) + EE + (size_t)NN * HD + NN + 2 * (size_t)KK1 +
       (size_t)NN * HD + 2 * (size_t)KK1 * HD + 2 * (size_t)KK1 +
       2 * (size_t)TB1 * 64 + 2 * (size_t)RB2 * 64 + 128) * 4
      + 24 * 256;
  size_t avail = ws_size > off ? ws_size - off : 0;
  int CH = (int)(avail / perSlot);
  if (CH > BB) CH = BB;
  if (CH < 1) CH = 1;

  int*   row_ofs = (int*)alloc((size_t)CH * (NN + 1) * 4);
  int*   esrc    = (int*)alloc((size_t)CH * EE * 4);
  float* h1      = (float*)alloc((size_t)CH * NN * HD * 4);
  float* score1  = (float*)alloc((size_t)CH * NN * 4);
  int*   sel1    = (int*)alloc((size_t)CH * KK1 * 4);
  float* t1      = (float*)alloc((size_t)CH * KK1 * 4);
  float* Zr      = (float*)alloc((size_t)CH * NN * HD * 4);   // orig-indexed
  float* Zn      = (float*)alloc((size_t)CH * KK1 * HD * 4);
  float* h2      = (float*)alloc((size_t)CH * KK1 * HD * 4);
  float* score2  = (float*)alloc((size_t)CH * KK1 * 4);
  int*   pos2    = (int*)alloc((size_t)CH * KK1 * 4);
  float* pmax    = (float*)alloc((size_t)CH * TB1 * 64 * 4);
  float* psum    = (float*)alloc((size_t)CH * TB1 * 64 * 4);
  float* p2max   = (float*)alloc((size_t)CH * RB2 * 64 * 4);
  float* p2sum   = (float*)alloc((size_t)CH * RB2 * 64 * 4);
  float* x1      = (float*)alloc((size_t)CH * 128 * 4);

  for (int g0 = 0; g0 < BB; g0 += CH) {
    int G = (BB - g0) < CH ? (BB - g0) : CH;
    int G8 = (G % 8 == 0) ? G / 8 : 0;
    k_csr<<<G, 1024, 0, stream>>>(ei, row_ofs, esrc, g0);
    k_h1f<<<G * 256, 256, 0, stream>>>(x, row_ofs, esrc, W1r, b1, W1n, p1, h1, score1, g0);
    k_select<<<G, 1024, 0, stream>>>(score1, NN, NN, KK1, sel1, KK1, nullptr, 0, t1, Zr);
    k_t2<<<G * TB1, 256, 0, stream>>>(h1, sel1, t1, W2r, W2n, Zr, Zn, pmax, psum);
    k_agg2<<<G * BPG2, 256, 0, stream>>>(row_ofs, esrc, sel1, Zr, Zn, b2, p2, h2, score2, G8);
    k_select<<<G, 1024, 0, stream>>>(score2, KK1, KK1, KK2, nullptr, 0, pos2, KK1, nullptr, nullptr);
    k_read1r<<<G, 64, 0, stream>>>(pmax, psum, x1);
    k_read2p<<<G * RB2, 256, 0, stream>>>(h2, pos2, score2, p2max, p2sum);
    k_read2r<<<G, 64, 0, stream>>>(p2max, p2sum, x1, feats, g0);
  }
  k_head<<<1, 256, 0, stream>>>(feats, Wa1, ba1, Wa5, ba5, out);
}

// Round 6
// 492.437 us; speedup vs baseline: 5.9077x; 1.1174x over previous
//
#include <hip/hip_runtime.h>
#include <float.h>
#include <math.h>

#define BB 64
#define NN 4096
#define EE 32768
#define FIN 12
#define HD 64
#define KK1 3277
#define KK2 2622
#define TB1 52   // ceil(KK1/64)
#define RB2 16   // blocks per graph for read2 partials
#define BPG2 820 // blocks per graph for agg2 (4 rows/block)

// ---------- CSR build: per-graph counting sort of edges by dst --------------
__global__ __launch_bounds__(1024) void k_csr(const int* __restrict__ ei,
    int* __restrict__ row_ofs, int* __restrict__ esrc, int g0) {
  __shared__ int cnt[NN];
  __shared__ int part[1024];
  int s = blockIdx.x, g = g0 + s, t = threadIdx.x;
  const int* src = ei + (size_t)g * 2 * EE;
  const int* dst = src + EE;
  for (int i = t; i < NN; i += 1024) cnt[i] = 0;
  __syncthreads();
  for (int e = t; e < EE; e += 1024) atomicAdd(&cnt[dst[e]], 1);
  __syncthreads();
  int c0 = cnt[t * 4], c1 = cnt[t * 4 + 1], c2 = cnt[t * 4 + 2], c3 = cnt[t * 4 + 3];
  int tot = c0 + c1 + c2 + c3;
  part[t] = tot;
  __syncthreads();
  for (int off = 1; off < 1024; off <<= 1) {
    int v = part[t];
    int add = (t >= off) ? part[t - off] : 0;
    __syncthreads();
    part[t] = v + add;
    __syncthreads();
  }
  int base = part[t] - tot;
  int b0 = base, b1 = base + c0, b2 = b1 + c1, b3 = b2 + c2;
  cnt[t * 4] = b0; cnt[t * 4 + 1] = b1; cnt[t * 4 + 2] = b2; cnt[t * 4 + 3] = b3;
  int* RO = row_ofs + (size_t)s * (NN + 1);
  RO[t * 4] = b0; RO[t * 4 + 1] = b1; RO[t * 4 + 2] = b2; RO[t * 4 + 3] = b3;
  if (t == 0) RO[NN] = EE;
  __syncthreads();
  int* ES = esrc + (size_t)s * EE;
  for (int e = t; e < EE; e += 1024) {
    int p = atomicAdd(&cnt[dst[e]], 1);
    ES[p] = src[e];
  }
}

// ---------- fused conv1: node-per-lane gather + per-lane matmul + score -----
// 16 blocks/graph, 256 thr: thread owns node. No shuffles; weights via LDS
// uniform broadcasts; XCD-affinity swizzle keeps each graph's X/ES in one L2.
__global__ __launch_bounds__(256) void k_h1f(const float* __restrict__ x,
    const int* __restrict__ row_ofs, const int* __restrict__ esrc,
    const float* __restrict__ W1r, const float* __restrict__ b1,
    const float* __restrict__ W1n, const float* __restrict__ p1,
    float* __restrict__ h1, float* __restrict__ score1, int g0, int G8) {
  __shared__ float sWr[64 * FIN], sWn[64 * FIN], sb[64], sp[64];
  int tid = threadIdx.x;
  for (int i = tid; i < 64 * FIN; i += 256) {  // W is [k][f] row-major: verbatim
    sWr[i] = W1r[i];
    sWn[i] = W1n[i];
  }
  if (tid < 64) { sb[tid] = b1[tid]; sp[tid] = p1[tid]; }
  __syncthreads();
  int b = blockIdx.x, s, nb;
  if (G8 > 0) { int hi = b >> 3; s = (b & 7) * G8 + hi / 16; nb = hi % 16; }
  else { s = b >> 4; nb = b & 15; }
  int node = nb * 256 + tid;
  int g = g0 + s;
  float nq = 0.f;
#pragma unroll
  for (int k = 0; k < 64; k++) nq += sp[k] * sp[k];
  float inv_norm = 1.0f / sqrtf(nq);
  const int* RO = row_ofs + (size_t)s * (NN + 1);
  const int* ES = esrc + (size_t)s * EE;
  const float4* X4 = (const float4*)(x + (size_t)g * NN * FIN);
  int r0 = RO[node], r1 = RO[node + 1];
  float a[FIN];
#pragma unroll
  for (int f = 0; f < FIN; f++) a[f] = 0.f;
  for (int i = r0; i < r1; i++) {
    int so = ES[i];
    float4 v0 = X4[(size_t)so * 3];
    float4 v1 = X4[(size_t)so * 3 + 1];
    float4 v2 = X4[(size_t)so * 3 + 2];
    a[0] += v0.x; a[1] += v0.y; a[2]  += v0.z; a[3]  += v0.w;
    a[4] += v1.x; a[5] += v1.y; a[6]  += v1.z; a[7]  += v1.w;
    a[8] += v2.x; a[9] += v2.y; a[10] += v2.z; a[11] += v2.w;
  }
  float xr[FIN];
  {
    float4 u0 = X4[(size_t)node * 3];
    float4 u1 = X4[(size_t)node * 3 + 1];
    float4 u2 = X4[(size_t)node * 3 + 2];
    xr[0] = u0.x; xr[1] = u0.y; xr[2]  = u0.z; xr[3]  = u0.w;
    xr[4] = u1.x; xr[5] = u1.y; xr[6]  = u1.z; xr[7]  = u1.w;
    xr[8] = u2.x; xr[9] = u2.y; xr[10] = u2.z; xr[11] = u2.w;
  }
  float* hrow = h1 + ((size_t)s * NN + node) * HD;
  float v = 0.f;
#pragma unroll
  for (int k0 = 0; k0 < 64; k0 += 4) {
    float4 hh;
#pragma unroll
    for (int c = 0; c < 4; c++) {
      int k = k0 + c;
      const float* wr = &sWr[k * FIN];
      const float* wn = &sWn[k * FIN];
      float acc = sb[k];
#pragma unroll
      for (int f = 0; f < FIN; f++) acc += a[f] * wr[f] + xr[f] * wn[f];
      acc = fmaxf(acc, 0.f);
      ((float*)&hh)[c] = acc;
      v += acc * sp[k];
    }
    *(float4*)&hrow[k0] = hh;
  }
  score1[(size_t)s * NN + node] = v * inv_norm;
}

// ---------- top-k select via in-LDS bitonic sort ----------------------------
// Stage 1: also zeroes Zr rows of DROPPED nodes (zr != nullptr).
__global__ __launch_bounds__(1024) void k_select(const float* __restrict__ score,
    int scStride, int nvalid, int K, int* __restrict__ sel, int selStride,
    int* __restrict__ pos, int posStride, float* __restrict__ tg,
    float* __restrict__ zr) {
  __shared__ unsigned long long sk[4096];
  int s = blockIdx.x;
  const float* sc = score + (size_t)s * scStride;
  for (int i = threadIdx.x; i < 4096; i += 1024) {
    unsigned long long c = 0ull;
    if (i < nvalid) {
      unsigned int b = __float_as_uint(sc[i]);
      unsigned int key = (b & 0x80000000u) ? ~b : (b | 0x80000000u);
      c = ((unsigned long long)key << 32) | (unsigned long long)(0xFFFFFFFFu - (unsigned int)i);
    }
    sk[i] = c;
  }
  __syncthreads();
  for (int k = 2; k <= 4096; k <<= 1) {
    for (int j = k >> 1; j > 0; j >>= 1) {
      for (int t = threadIdx.x; t < 2048; t += 1024) {
        int low = t & (j - 1);
        int i = ((t & ~(j - 1)) << 1) | low;
        int ix = i | j;
        bool down = ((i & k) == 0);
        unsigned long long A = sk[i], Bv = sk[ix];
        bool sw = down ? (A < Bv) : (A > Bv);
        if (sw) { sk[i] = Bv; sk[ix] = A; }
      }
      __syncthreads();
    }
  }
  for (int r = threadIdx.x; r < 4096; r += 1024) {
    if (r < nvalid) {
      int idx = (int)(0xFFFFFFFFu - (unsigned int)(sk[r] & 0xFFFFFFFFull));
      if (r < K) {
        if (sel) sel[(size_t)s * selStride + r] = idx;
        if (pos) pos[(size_t)s * posStride + idx] = r;
        if (tg) tg[(size_t)s * selStride + r] = tanhf(sc[idx]);
      } else {
        if (pos) pos[(size_t)s * posStride + idx] = -1;
        if (zr) {
          float4* zp = (float4*)(zr + ((size_t)s * NN + idx) * 64);
#pragma unroll
          for (int q = 0; q < 16; q++) zp[q] = make_float4(0.f, 0.f, 0.f, 0.f);
        }
      }
    }
  }
}

// ---------- k_t2: Z = (t*h1[sel]) @ [W2r^T | W2n^T]; fused read1 partials ---
// Zr is ORIG-indexed (NN rows/graph, dropped rows pre-zeroed by k_select).
__global__ __launch_bounds__(256) void k_t2(const float* __restrict__ h1,
    const int* __restrict__ sel1, const float* __restrict__ t1,
    const float* __restrict__ W2r, const float* __restrict__ W2n,
    float* __restrict__ Zr, float* __restrict__ Zn,
    float* __restrict__ pmax, float* __restrict__ psum) {
  __shared__ float sW[64 * 128];       // sW[k*128 + c]: c<64 -> W2r, else W2n
  __shared__ float sG[64 * 68];        // padded stride 68
  __shared__ float redm[4][64], reds[4][64];
  __shared__ int sOrig[64];
  int s = blockIdx.x / TB1;
  int tb = blockIdx.x % TB1;
  int j0 = tb * 64;
  int nv = KK1 - j0; if (nv > 64) nv = 64;
  int tid = threadIdx.x;
  for (int i = tid; i < 64 * 128; i += 256) {
    int k = i >> 7, c = i & 127;
    sW[i] = (c < 64) ? W2r[c * 64 + k] : W2n[(c - 64) * 64 + k];
  }
  {
    int r = tid >> 2, q = tid & 3;
    float4 v0 = {0.f,0.f,0.f,0.f}, v1 = v0, v2 = v0, v3 = v0;
    if (r < nv) {
      int j = j0 + r;
      int orig = sel1[(size_t)s * KK1 + j];
      if (q == 0) sOrig[r] = orig;
      float t = t1[(size_t)s * KK1 + j];
      const float4* hr = (const float4*)(h1 + ((size_t)s * NN + orig) * HD + q * 16);
      v0 = hr[0]; v1 = hr[1]; v2 = hr[2]; v3 = hr[3];
      v0.x *= t; v0.y *= t; v0.z *= t; v0.w *= t;
      v1.x *= t; v1.y *= t; v1.z *= t; v1.w *= t;
      v2.x *= t; v2.y *= t; v2.z *= t; v2.w *= t;
      v3.x *= t; v3.y *= t; v3.z *= t; v3.w *= t;
    }
    float* gw = &sG[r * 68 + q * 16];
    ((float4*)gw)[0] = v0; ((float4*)gw)[1] = v1;
    ((float4*)gw)[2] = v2; ((float4*)gw)[3] = v3;
  }
  __syncthreads();
  {
    int c = tid & 63, qq = tid >> 6;
    float mx = -FLT_MAX, sm = 0.f;
    int rend = qq * 16 + 16; if (rend > nv) rend = nv;
    for (int rr = qq * 16; rr < rend; rr++) {
      float v = sG[rr * 68 + c];
      mx = fmaxf(mx, v); sm += v;
    }
    redm[qq][c] = mx; reds[qq][c] = sm;
  }
  __syncthreads();
  if (tid < 64) {
    float mx = redm[0][tid], sm = reds[0][tid];
    for (int qq = 1; qq < 4; qq++) { mx = fmaxf(mx, redm[qq][tid]); sm += reds[qq][tid]; }
    pmax[((size_t)s * TB1 + tb) * 64 + tid] = mx;
    psum[((size_t)s * TB1 + tb) * 64 + tid] = sm;
  }
  int rg = tid >> 5;
  int c0 = (tid & 31) * 4;
  float acc[8][4];
#pragma unroll
  for (int i = 0; i < 8; i++)
#pragma unroll
    for (int cc = 0; cc < 4; cc++) acc[i][cc] = 0.f;
  for (int k = 0; k < 64; k += 4) {
    float4 w0 = *(const float4*)&sW[(k + 0) * 128 + c0];
    float4 w1 = *(const float4*)&sW[(k + 1) * 128 + c0];
    float4 w2 = *(const float4*)&sW[(k + 2) * 128 + c0];
    float4 w3 = *(const float4*)&sW[(k + 3) * 128 + c0];
#pragma unroll
    for (int i = 0; i < 8; i++) {
      float4 g = *(const float4*)&sG[(rg * 8 + i) * 68 + k];
      acc[i][0] += g.x * w0.x + g.y * w1.x + g.z * w2.x + g.w * w3.x;
      acc[i][1] += g.x * w0.y + g.y * w1.y + g.z * w2.y + g.w * w3.y;
      acc[i][2] += g.x * w0.z + g.y * w1.z + g.z * w2.z + g.w * w3.z;
      acc[i][3] += g.x * w0.w + g.y * w1.w + g.z * w2.w + g.w * w3.w;
    }
  }
#pragma unroll
  for (int i = 0; i < 8; i++) {
    int j = j0 + rg * 8 + i;
    if (j < KK1) {
      float4 v = {acc[i][0], acc[i][1], acc[i][2], acc[i][3]};
      if (c0 < 64) *(float4*)&Zr[((size_t)s * NN + sOrig[rg * 8 + i]) * 64 + c0] = v;
      else         *(float4*)&Zn[((size_t)s * KK1 + j) * 64 + (c0 - 64)] = v;
    }
  }
}

// ---------- k_agg2: h2 = relu(b2 + Zn[j] + sum_{e: dst=d} Zr[src]); score2 --
// Branchless: Zr rows of dropped srcs are zero. XCD-affinity swizzle.
__global__ __launch_bounds__(256) void k_agg2(const int* __restrict__ row_ofs,
    const int* __restrict__ esrc, const int* __restrict__ sel1,
    const float* __restrict__ Zr, const float* __restrict__ Zn,
    const float* __restrict__ b2, const float* __restrict__ p2,
    float* __restrict__ h2, float* __restrict__ score2, int G8) {
  int b = blockIdx.x;
  int s, jb;
  if (G8 > 0) {                 // all blocks of graph s land on XCD s/G8
    int hi = b >> 3;
    s = (b & 7) * G8 + hi / BPG2;
    jb = hi % BPG2;
  } else { s = b / BPG2; jb = b % BPG2; }
  int j = jb * 4 + (threadIdx.x >> 6);
  int lane = threadIdx.x & 63;
  float pk = p2[lane];
  float nq = pk * pk;
#pragma unroll
  for (int o = 32; o; o >>= 1) nq += __shfl_xor(nq, o, 64);
  float inv_norm = 1.0f / sqrtf(nq);
  if (j >= KK1) return;
  const int* RO = row_ofs + (size_t)s * (NN + 1);
  const int* ES = esrc + (size_t)s * EE;
  int d = sel1[(size_t)s * KK1 + j];
  int r0 = RO[d], r1 = RO[d + 1];
  float acc = b2[lane] + Zn[((size_t)s * KK1 + j) * 64 + lane];
  float a0 = 0.f, a1 = 0.f, a2 = 0.f, a3 = 0.f;
  const float* ZRb = Zr + (size_t)s * NN * 64;
  for (int base = r0; base < r1; base += 64) {
    int n = r1 - base; if (n > 64) n = 64;
    int srow = 0;
    if (base + lane < r1) srow = ES[base + lane];
    int i = 0;
    for (; i + 4 <= n; i += 4) {
      int s0 = __shfl(srow, i, 64),     s1 = __shfl(srow, i + 1, 64);
      int s2 = __shfl(srow, i + 2, 64), s3 = __shfl(srow, i + 3, 64);
      a0 += ZRb[(size_t)s0 * 64 + lane];
      a1 += ZRb[(size_t)s1 * 64 + lane];
      a2 += ZRb[(size_t)s2 * 64 + lane];
      a3 += ZRb[(size_t)s3 * 64 + lane];
    }
    for (; i < n; i++) acc += ZRb[(size_t)__shfl(srow, i, 64) * 64 + lane];
  }
  acc += (a0 + a1) + (a2 + a3);
  float h = fmaxf(acc, 0.f);
  h2[((size_t)s * KK1 + j) * 64 + lane] = h;
  float v = h * pk;
#pragma unroll
  for (int o = 32; o; o >>= 1) v += __shfl_xor(v, o, 64);
  if (lane == 0) score2[(size_t)s * KK1 + j] = v * inv_norm;
}

// ---------- read1 final reduce over k_t2 partials ---------------------------
__global__ __launch_bounds__(64) void k_read1r(const float* __restrict__ pmax,
    const float* __restrict__ psum, float* __restrict__ x1) {
  int s = blockIdx.x, k = threadIdx.x;
  float mx = -FLT_MAX, sm = 0.f;
  for (int t = 0; t < TB1; t++) {
    mx = fmaxf(mx, pmax[((size_t)s * TB1 + t) * 64 + k]);
    sm += psum[((size_t)s * TB1 + t) * 64 + k];
  }
  x1[(size_t)s * 128 + k] = mx;
  x1[(size_t)s * 128 + 64 + k] = sm / (float)KK1;
}

// ---------- read2 partials: stream h2 rows, mask by pos2 --------------------
__global__ __launch_bounds__(256) void k_read2p(const float* __restrict__ h2,
    const int* __restrict__ pos2, const float* __restrict__ score2,
    float* __restrict__ p2max, float* __restrict__ p2sum) {
  int s = blockIdx.x / RB2, pb = blockIdx.x % RB2;
  int lane = threadIdx.x & 63, wave = threadIdx.x >> 6;
  const int ROWS = (KK1 + RB2 - 1) / RB2;  // 205
  int j0 = pb * ROWS;
  int j1 = j0 + ROWS; if (j1 > KK1) j1 = KK1;
  float mx = -FLT_MAX, sm = 0.f;
  for (int j = j0 + wave; j < j1; j += 4) {
    if (pos2[(size_t)s * KK1 + j] >= 0) {
      float t = tanhf(score2[(size_t)s * KK1 + j]);
      float v = h2[((size_t)s * KK1 + j) * HD + lane] * t;
      mx = fmaxf(mx, v); sm += v;
    }
  }
  __shared__ float smx[4][64], ssm[4][64];
  smx[wave][lane] = mx; ssm[wave][lane] = sm;
  __syncthreads();
  if (wave == 0) {
    for (int q = 1; q < 4; q++) { mx = fmaxf(mx, smx[q][lane]); sm += ssm[q][lane]; }
    p2max[((size_t)s * RB2 + pb) * 64 + lane] = mx;
    p2sum[((size_t)s * RB2 + pb) * 64 + lane] = sm;
  }
}

// ---------- read2 final reduce + combine: feats = x1 + x2 -------------------
__global__ __launch_bounds__(64) void k_read2r(const float* __restrict__ p2max,
    const float* __restrict__ p2sum, const float* __restrict__ x1,
    float* __restrict__ feats, int g0) {
  int s = blockIdx.x, k = threadIdx.x;
  float mx = -FLT_MAX, sm = 0.f;
  for (int t = 0; t < RB2; t++) {
    mx = fmaxf(mx, p2max[((size_t)s * RB2 + t) * 64 + k]);
    sm += p2sum[((size_t)s * RB2 + t) * 64 + k];
  }
  feats[(size_t)(g0 + s) * 128 + k] = x1[(size_t)s * 128 + k] + mx;
  feats[(size_t)(g0 + s) * 128 + 64 + k] = x1[(size_t)s * 128 + 64 + k] + sm / (float)KK2;
}

// ---------- head: MLP + softmax across graphs (axis 0) ----------------------
__global__ __launch_bounds__(256) void k_head(const float* __restrict__ feats,
    const float* __restrict__ Wa1, const float* __restrict__ ba1,
    const float* __restrict__ Wa5, const float* __restrict__ ba5,
    float* __restrict__ out) {
  __shared__ float sF[BB * 128];
  __shared__ float sA1[BB * 64];
  __shared__ float sA5[BB * 10];
  for (int i = threadIdx.x; i < BB * 128; i += 256) sF[i] = feats[i];
  __syncthreads();
  for (int o = threadIdx.x; o < BB * 64; o += 256) {
    int b = o >> 6, j = o & 63;
    float acc = ba1[j];
    for (int i = 0; i < 128; i++) acc += sF[b * 128 + i] * Wa1[j * 128 + i];
    sA1[o] = fmaxf(acc, 0.f);
  }
  __syncthreads();
  for (int o = threadIdx.x; o < BB * 10; o += 256) {
    int b = o / 10, c = o % 10;
    float acc = ba5[c];
    for (int j = 0; j < 64; j++) acc += sA1[b * 64 + j] * Wa5[c * 64 + j];
    sA5[o] = acc;
  }
  __syncthreads();
  if (threadIdx.x < 10) {
    int c = threadIdx.x;
    float m = -FLT_MAX;
    for (int b = 0; b < BB; b++) m = fmaxf(m, sA5[b * 10 + c]);
    float sum = 0.f;
    for (int b = 0; b < BB; b++) sum += expf(sA5[b * 10 + c] - m);
    float inv = 1.0f / sum;
    for (int b = 0; b < BB; b++) out[b * 10 + c] = expf(sA5[b * 10 + c] - m) * inv;
  }
}

extern "C" void kernel_launch(void* const* d_in, const int* in_sizes, int n_in,
                              void* d_out, int out_size, void* d_ws, size_t ws_size,
                              hipStream_t stream) {
  const float* x   = (const float*)d_in[0];
  const int*   ei  = (const int*)d_in[1];
  const float* W1r = (const float*)d_in[2];
  const float* b1  = (const float*)d_in[3];
  const float* W1n = (const float*)d_in[4];
  const float* p1  = (const float*)d_in[5];
  const float* W2r = (const float*)d_in[6];
  const float* b2  = (const float*)d_in[7];
  const float* W2n = (const float*)d_in[8];
  const float* p2  = (const float*)d_in[9];
  const float* Wa1 = (const float*)d_in[10];
  const float* ba1 = (const float*)d_in[11];
  const float* Wa5 = (const float*)d_in[12];
  const float* ba5 = (const float*)d_in[13];
  float* out = (float*)d_out;

  char* base = (char*)d_ws;
  size_t off = 0;
  auto alloc = [&](size_t bytes) -> void* {
    void* p = base + off;
    off = (off + bytes + 255) & ~(size_t)255;
    return p;
  };
  float* feats = (float*)alloc((size_t)BB * 128 * 4);

  const size_t perSlot =
      ((size_t)(NN + 1) + EE + (size_t)NN * HD + NN + 2 * (size_t)KK1 +
       (size_t)NN * HD + 2 * (size_t)KK1 * HD + 2 * (size_t)KK1 +
       2 * (size_t)TB1 * 64 + 2 * (size_t)RB2 * 64 + 128) * 4
      + 24 * 256;
  size_t avail = ws_size > off ? ws_size - off : 0;
  int CH = (int)(avail / perSlot);
  if (CH > BB) CH = BB;
  if (CH < 1) CH = 1;

  int*   row_ofs = (int*)alloc((size_t)CH * (NN + 1) * 4);
  int*   esrc    = (int*)alloc((size_t)CH * EE * 4);
  float* h1      = (float*)alloc((size_t)CH * NN * HD * 4);
  float* score1  = (float*)alloc((size_t)CH * NN * 4);
  int*   sel1    = (int*)alloc((size_t)CH * KK1 * 4);
  float* t1      = (float*)alloc((size_t)CH * KK1 * 4);
  float* Zr      = (float*)alloc((size_t)CH * NN * HD * 4);   // orig-indexed
  float* Zn      = (float*)alloc((size_t)CH * KK1 * HD * 4);
  float* h2      = (float*)alloc((size_t)CH * KK1 * HD * 4);
  float* score2  = (float*)alloc((size_t)CH * KK1 * 4);
  int*   pos2    = (int*)alloc((size_t)CH * KK1 * 4);
  float* pmax    = (float*)alloc((size_t)CH * TB1 * 64 * 4);
  float* psum    = (float*)alloc((size_t)CH * TB1 * 64 * 4);
  float* p2max   = (float*)alloc((size_t)CH * RB2 * 64 * 4);
  float* p2sum   = (float*)alloc((size_t)CH * RB2 * 64 * 4);
  float* x1      = (float*)alloc((size_t)CH * 128 * 4);

  for (int g0 = 0; g0 < BB; g0 += CH) {
    int G = (BB - g0) < CH ? (BB - g0) : CH;
    int G8 = (G % 8 == 0) ? G / 8 : 0;
    k_csr<<<G, 1024, 0, stream>>>(ei, row_ofs, esrc, g0);
    k_h1f<<<G * 16, 256, 0, stream>>>(x, row_ofs, esrc, W1r, b1, W1n, p1, h1, score1, g0, G8);
    k_select<<<G, 1024, 0, stream>>>(score1, NN, NN, KK1, sel1, KK1, nullptr, 0, t1, Zr);
    k_t2<<<G * TB1, 256, 0, stream>>>(h1, sel1, t1, W2r, W2n, Zr, Zn, pmax, psum);
    k_agg2<<<G * BPG2, 256, 0, stream>>>(row_ofs, esrc, sel1, Zr, Zn, b2, p2, h2, score2, G8);
    k_select<<<G, 1024, 0, stream>>>(score2, KK1, KK1, KK2, nullptr, 0, pos2, KK1, nullptr, nullptr);
    k_read1r<<<G, 64, 0, stream>>>(pmax, psum, x1);
    k_read2p<<<G * RB2, 256, 0, stream>>>(h2, pos2, score2, p2max, p2sum);
    k_read2r<<<G, 64, 0, stream>>>(p2max, p2sum, x1, feats, g0);
  }
  k_head<<<1, 256, 0, stream>>>(feats, Wa1, ba1, Wa5, ba5, out);
}